// Round 9
// baseline (630.030 us; speedup 1.0000x reference)
//
#include <hip/hip_runtime.h>
#include <cstddef>

// PointNet++ set-abstraction pipeline (B=16, N=4096, HC=64).
// R9: R8 with the compile fix — fps stash generalized back to NSTASH slots
// (fps2 has NPOINT=128 > THREADS=64). fps1 runs at 1024 threads / 4 pts-thread
// so the live set (~36 regs) fits naturally below the spill threshold.

#define EPSB 1e-5f
constexpr int SLOTS1 = 16;
constexpr int SLOTS2 = 64;

static __device__ __forceinline__ unsigned long long umax64(unsigned long long a,
                                                            unsigned long long b)
{
    return a > b ? a : b;
}

static __device__ __forceinline__ unsigned pack_bf16x2(float a, float b)
{
    unsigned ua = __float_as_uint(a), ub = __float_as_uint(b);
    ua += 0x7fffu + ((ua >> 16) & 1u);
    ub += 0x7fffu + ((ub >> 16) & 1u);
    return (ua >> 16) | (ub & 0xffff0000u);
}

static __device__ __forceinline__ unsigned short bf16_of(float a)
{
    unsigned u = __float_as_uint(a);
    u += 0x7fffu + ((u >> 16) & 1u);
    return (unsigned short)(u >> 16);
}

// Full-wave u64 max via DPP (row_shr 1/2/4/8 + row_bcast15/31), broadcast to
// all lanes via readlane 63. All 64 lanes must be active.
static __device__ __forceinline__ unsigned long long wave_umax64_dpp(unsigned long long x)
{
#define DPP_STEP(ctrl, rmask)                                                        \
    {                                                                                \
        int lo_ = __builtin_amdgcn_update_dpp(0, (int)(unsigned)x, ctrl, rmask, 0xf, false); \
        int hi_ = __builtin_amdgcn_update_dpp(0, (int)(unsigned)(x >> 32), ctrl, rmask, 0xf, false); \
        unsigned long long c_ = ((unsigned long long)(unsigned)hi_ << 32) | (unsigned)lo_; \
        x = umax64(x, c_);                                                           \
    }
    DPP_STEP(0x111, 0xf)
    DPP_STEP(0x112, 0xf)
    DPP_STEP(0x114, 0xf)
    DPP_STEP(0x118, 0xf)
    DPP_STEP(0x142, 0xa)
    DPP_STEP(0x143, 0xc)
#undef DPP_STEP
    unsigned lo = (unsigned)__builtin_amdgcn_readlane((int)(unsigned)x, 63);
    unsigned hi = (unsigned)__builtin_amdgcn_readlane((int)(unsigned)(x >> 32), 63);
    return ((unsigned long long)hi << 32) | lo;
}

// ---------------- FPS body ----------------
// jax scan semantics: idx[0]=0; dist=min(dist,|x-c|^2); next=argmax (first-index
// ties). Key: hi = dist bits (>=0), lo = ~gidx (max -> smallest index).
template<int N, int NPOINT, int THREADS>
__device__ __forceinline__ void fps_body(int t,
        float4* cmir, unsigned long long* kslots,
        const float* __restrict__ xyz, int bStride, int cStride, int nStride,
        int b, float* __restrict__ nxyz, float* __restrict__ lxyz)
{
    constexpr int PT = N / THREADS;
    constexpr int NW = THREADS / 64;
    constexpr int NSTASH = (NPOINT + THREADS - 1) / THREADS;
    const float* xb = xyz + (size_t)b * bStride;

    float px[PT], py[PT], pz[PT], dist[PT];
#pragma unroll
    for (int i = 0; i < PT; ++i) {
        int p = t + i * THREADS;
        px[i] = xb[(size_t)0 * cStride + (size_t)p * nStride];
        py[i] = xb[(size_t)1 * cStride + (size_t)p * nStride];
        pz[i] = xb[(size_t)2 * cStride + (size_t)p * nStride];
        if constexpr (NW > 1) cmir[p] = make_float4(px[i], py[i], pz[i], 0.f);
        dist[i] = 1e10f;
    }

    float stx[NSTASH], sty[NSTASH], stz[NSTASH];
#pragma unroll
    for (int i = 0; i < NSTASH; ++i) { stx[i] = 0.f; sty[i] = 0.f; stz[i] = 0.f; }

    // round 0 = point 0 (uniform scalar loads)
    float cx = xb[0], cy = xb[(size_t)cStride], cz = xb[(size_t)2 * cStride];
    if (t == 0) { stx[0] = cx; sty[0] = cy; stz[0] = cz; }
    if constexpr (NW > 1) __syncthreads();   // mirror ready

    for (int it = 1; it < NPOINT; ++it) {
        // keep coord regs resident (satisfiable at small PT; no spill pressure)
#pragma unroll
        for (int i = 0; i < PT; ++i)
            asm volatile("" : "+v"(px[i]), "+v"(py[i]), "+v"(pz[i]));

        float bv = -1.0f; int bidx = 0;
        float bx = 0.f, by = 0.f, bz = 0.f;   // used only in NW==1 path
#pragma unroll
        for (int i = 0; i < PT; ++i) {
            float dx = px[i] - cx, dy = py[i] - cy, dz = pz[i] - cz;
            float d = __builtin_fmaf(dx, dx, __builtin_fmaf(dy, dy, dz * dz));
            float nd = fminf(dist[i], d);
            dist[i] = nd;
            bool g = nd > bv;      // strict >: keeps lowest index within lane
            bv = g ? nd : bv;
            bidx = g ? (t + i * THREADS) : bidx;
            if constexpr (NW == 1) {
                bx = g ? px[i] : bx; by = g ? py[i] : by; bz = g ? pz[i] : bz;
            }
        }
        unsigned long long mykey =
            ((unsigned long long)__float_as_uint(bv) << 32) | (unsigned)(~bidx);
        unsigned long long wkey = wave_umax64_dpp(mykey);
        if constexpr (NW > 1) {
            const int pb = it & 1;
            if ((t & 63) == 0) kslots[pb * NW + (t >> 6)] = wkey;
            __syncthreads();
            const ulonglong2* kp = (const ulonglong2*)(kslots + pb * NW);
            unsigned long long m = wkey;
#pragma unroll
            for (int w2 = 0; w2 < NW / 2; ++w2) {   // broadcast reads (same addr)
                ulonglong2 kk = kp[w2];
                m = umax64(m, umax64(kk.x, kk.y));
            }
            int widx = (int)(~(unsigned)m);
            float4 c = cmir[widx];   // single broadcast ds_read_b128
            cx = c.x; cy = c.y; cz = c.z;
        } else {
            unsigned long long ball = __ballot(mykey == wkey);
            int wl = __ffsll(ball) - 1;   // uniform winner lane
            cx = __int_as_float(__builtin_amdgcn_readlane(__float_as_int(bx), wl));
            cy = __int_as_float(__builtin_amdgcn_readlane(__float_as_int(by), wl));
            cz = __int_as_float(__builtin_amdgcn_readlane(__float_as_int(bz), wl));
        }
        if constexpr (NSTASH == 1) {
            if (t == it) { stx[0] = cx; sty[0] = cy; stz[0] = cz; }
        } else {
            if ((it & (THREADS - 1)) == t) {
                if (it >= THREADS) { stx[1] = cx; sty[1] = cy; stz[1] = cz; }
                else               { stx[0] = cx; sty[0] = cy; stz[0] = cz; }
            }
        }
    }
#pragma unroll
    for (int s2 = 0; s2 < NSTASH; ++s2) {
        int s = t + s2 * THREADS;
        if (s < NPOINT) {
            nxyz[(size_t)(b * NPOINT + s) * 3 + 0] = stx[s2];
            nxyz[(size_t)(b * NPOINT + s) * 3 + 1] = sty[s2];
            nxyz[(size_t)(b * NPOINT + s) * 3 + 2] = stz[s2];
            lxyz[(size_t)b * 3 * NPOINT + 0 * NPOINT + s] = stx[s2];
            lxyz[(size_t)b * 3 * NPOINT + 1 * NPOINT + s] = sty[s2];
            lxyz[(size_t)b * 3 * NPOINT + 2 * NPOINT + s] = stz[s2];
        }
    }
}

// ---------------- Mega-kernel 1 (1024 threads): fps1 + project6 + w2t x3 + zero -------
__global__ __launch_bounds__(1024)
void mega1_kernel(const float* __restrict__ l0_xyz, const float* __restrict__ l0_pts,
                  const float* __restrict__ w11, const float* __restrict__ b11,
                  float* __restrict__ p1,
                  float* __restrict__ nxyz1, float* __restrict__ o_l1xyz,
                  const float* __restrict__ w12, unsigned short* __restrict__ w12t,
                  const float* __restrict__ w22, unsigned short* __restrict__ w22t,
                  const float* __restrict__ w32, unsigned short* __restrict__ w32t,
                  float* __restrict__ stats)
{
    __shared__ __attribute__((aligned(16))) float4 cmir[4096];
    __shared__ __attribute__((aligned(16))) unsigned long long kxs[32];
    int blk = blockIdx.x;
    const int tid = threadIdx.x;
    if (blk < 16) {   // FPS SA1: 1024 thr, 4 pts/thread
        fps_body<4096, 256, 1024>(tid, cmir, kxs,
                                  l0_xyz, 3 * 4096, 4096, 1, blk, nxyz1, o_l1xyz);
        return;
    }
    blk -= 16;
    if (blk < 4096) {  // project6: p1[b,n,64] = [xyz,pts]·W1 + b1
        int idx = blk * 1024 + tid;
        int d = idx & 63;
        int n = (idx >> 6) & 4095;
        int b = idx >> 18;
        const float* xb = l0_xyz + (size_t)b * 3 * 4096 + n;
        const float* pb = l0_pts + (size_t)b * 3 * 4096 + n;
        float a0 = xb[0], a1 = xb[4096], a2 = xb[2 * 4096];
        float a3 = pb[0], a4 = pb[4096], a5 = pb[2 * 4096];
        float acc = b11[d];
        acc += a0 * w11[d] + a1 * w11[64 + d] + a2 * w11[128 + d];
        acc += a3 * w11[192 + d] + a4 * w11[256 + d] + a5 * w11[320 + d];
        p1[idx] = acc;
        return;
    }
    blk -= 4096;
    if (blk < 8) {     // w12t: 64x128
        int i = blk * 1024 + tid;
        if (i < 64 * 128) { int k = i / 128, n = i % 128; w12t[(size_t)n * 64 + k] = bf16_of(w12[i]); }
        return;
    }
    blk -= 8;
    if (blk < 32) {    // w22t: 128x256
        int i = blk * 1024 + tid;
        if (i < 128 * 256) { int k = i / 256, n = i % 256; w22t[(size_t)n * 128 + k] = bf16_of(w22[i]); }
        return;
    }
    blk -= 32;
    if (blk < 128) {   // w32t: 256x512
        int i = blk * 1024 + tid;
        if (i < 256 * 512) { int k = i / 512, n = i % 512; w32t[(size_t)n * 256 + k] = bf16_of(w32[i]); }
        return;
    }
    blk -= 128;
    {                  // zero the stats arena
        int i = blk * 1024 + tid;
        if (i < 129024) stats[i] = 0.f;
    }
}

// ---------------- Ball query + q projection + fused BN1 stats (+opt fps2) -------------
// 256 threads = 4 waves; one ball per wave.
template<int NS, int D, bool WITHFPS>
__global__ __launch_bounds__(256)
void ballstat_kernel(const float* __restrict__ xyz, int bStride, int cStride, int nStride, int N,
                     const float* __restrict__ nxyz, int S, float r2,
                     int* __restrict__ gi,
                     const float* __restrict__ W, float* __restrict__ q,
                     const float* __restrict__ p, float* __restrict__ slots,
                     const float* __restrict__ fxyz, float* __restrict__ fnxyz,
                     float* __restrict__ flxyz)
{
    __shared__ int sgo[4][NS];
    const int wid = threadIdx.x >> 6, l = threadIdx.x & 63;
    int g = blockIdx.x * 4 + wid;
    if constexpr (WITHFPS) {
        if (g < 16) {
            fps_body<256, 128, 64>(l, nullptr, nullptr,
                                   fxyz, 768, 1, 3, g, fnxyz, flxyz);
            return;
        }
        g -= 16;
    }
    constexpr int DL = D / 64;
    const int bs = g;
    const int b = bs / S;
    float cx = nxyz[(size_t)bs * 3 + 0], cy = nxyz[(size_t)bs * 3 + 1], cz = nxyz[(size_t)bs * 3 + 2];
    float s2 = cx * cx + cy * cy + cz * cz;
    const float* xb = xyz + (size_t)b * bStride;
    int cnt = 0;
    int first = N - 1;
    int* go = gi + (size_t)bs * NS;
    for (int base = 0; base < N; base += 64) {
        int n = base + l;
        float x = xb[(size_t)0 * cStride + (size_t)n * nStride];
        float y = xb[(size_t)1 * cStride + (size_t)n * nStride];
        float z = xb[(size_t)2 * cStride + (size_t)n * nStride];
        float x2 = x * x + y * y + z * z;
        float dot = cx * x + cy * y + cz * z;
        float sqr = (s2 + x2) - 2.0f * dot;   // reference expansion form
        bool pass = (sqr <= r2);
        unsigned long long m = __ballot(pass);
        if (cnt == 0 && m) first = base + (__ffsll((unsigned long long)m) - 1);
        int pos = cnt + __popcll(m & ((1ull << l) - 1ull));
        if (pass && pos < NS) { go[pos] = n; sgo[wid][pos] = n; }
        cnt += __popcll(m);
        if (cnt >= NS) break;
    }
    if (cnt < NS && l >= cnt && l < NS) { go[l] = first; sgo[wid][l] = first; }

    float qv[DL];
#pragma unroll
    for (int j = 0; j < DL; ++j) {
        int d = j * 64 + l;
        qv[j] = cx * W[d] + cy * W[D + d] + cz * W[2 * D + d];
        q[(size_t)bs * D + d] = qv[j];
    }
    float s[DL], ss[DL];
#pragma unroll
    for (int j = 0; j < DL; ++j) { s[j] = 0.f; ss[j] = 0.f; }
#pragma unroll 4
    for (int k = 0; k < NS; ++k) {
        int idx = sgo[wid][k];
        const float* pr = p + (size_t)(b * N + idx) * D;
#pragma unroll
        for (int j = 0; j < DL; ++j) {
            float v = pr[j * 64 + l] - qv[j];
            s[j] += v; ss[j] += v * v;
        }
    }
    int slot = bs & (SLOTS1 - 1);
#pragma unroll
    for (int j = 0; j < DL; ++j) {
        int d = j * 64 + l;
        atomicAdd(&slots[(size_t)(slot * 2 + 0) * D + d], s[j]);
        atomicAdd(&slots[(size_t)(slot * 2 + 1) * D + d], ss[j]);
    }
}

// ---------------- MFMA layer-2 with inline BN1 finalize ----------------
template<int KS, int CIN, int COUTB>
__global__ __launch_bounds__(512, 2)
void mfma_gemm_kernel(const float* __restrict__ p, const float* __restrict__ q,
                      const int* __restrict__ gi, int S, int NCH, int N,
                      const float* __restrict__ st1, float m1cnt,
                      const float* __restrict__ g1, const float* __restrict__ be1,
                      const unsigned short* __restrict__ w2t, int coutFull,
                      const float* __restrict__ b2,
                      float* __restrict__ st2,
                      float* __restrict__ mx, float* __restrict__ mn)
{
    constexpr int MT = KS / 16;
    constexpr int NSL = 8 / MT;
    constexpr int SLW = COUTB / NSL;
    constexpr int TPW = SLW / 16;
    constexpr int KST = CIN / 32;
    constexpr int LDA = CIN + 8;
    typedef __attribute__((ext_vector_type(8))) short bf16x8;
    typedef __attribute__((ext_vector_type(4))) float f32x4;

    __shared__ __attribute__((aligned(16))) unsigned short hl[KS][LDA];
    __shared__ float red[4][8][SLW];
    __shared__ __attribute__((aligned(16))) float ss_scale[CIN];
    __shared__ __attribute__((aligned(16))) float ss_shift[CIN];

    const int chunk = blockIdx.x % NCH;
    const int bs = blockIdx.x / NCH;
    const int b = bs / S;
    const int tid = threadIdx.x;
    const int c2_0 = chunk * COUTB;
    const int w = tid >> 6, lane = tid & 63;
    const int mt = w % MT, ns = w / MT;
    const int lrow = lane & 15, quad = lane >> 4;

    for (int c = tid; c < CIN; c += 512) {
        float s0 = 0.f, s1 = 0.f;
        for (int sl = 0; sl < SLOTS1; ++sl) {
            s0 += st1[(size_t)(sl * 2 + 0) * CIN + c];
            s1 += st1[(size_t)(sl * 2 + 1) * CIN + c];
        }
        float mean = s0 / m1cnt;
        float var = s1 / m1cnt - mean * mean;
        float inv = 1.0f / sqrtf(var + EPSB);
        float scl = g1[c] * inv;
        ss_scale[c] = scl;
        ss_shift[c] = be1[c] - scl * mean;
    }
    __syncthreads();

    constexpr int ITER = KS * CIN / (512 * 4);
    const int gbase = bs * KS;
#pragma unroll
    for (int it = 0; it < ITER; ++it) {
        int e = (it * 512 + tid) * 4;
        int k = e / CIN, c = e % CIN;
        int row = gi ? (b * N + gi[gbase + k]) : (b * KS + k);
        float4 v = *(const float4*)&p[(size_t)row * CIN + c];
        if (q) {
            float4 qq = *(const float4*)&q[(size_t)bs * CIN + c];
            v.x -= qq.x; v.y -= qq.y; v.z -= qq.z; v.w -= qq.w;
        }
        float4 sc = *(const float4*)&ss_scale[c];
        float4 sh = *(const float4*)&ss_shift[c];
        v.x = fmaxf(__builtin_fmaf(sc.x, v.x, sh.x), 0.f);
        v.y = fmaxf(__builtin_fmaf(sc.y, v.y, sh.y), 0.f);
        v.z = fmaxf(__builtin_fmaf(sc.z, v.z, sh.z), 0.f);
        v.w = fmaxf(__builtin_fmaf(sc.w, v.w, sh.w), 0.f);
        uint2 pk;
        pk.x = pack_bf16x2(v.x, v.y);
        pk.y = pack_bf16x2(v.z, v.w);
        *(uint2*)&hl[k][c] = pk;
    }
    __syncthreads();

    f32x4 acc[TPW];
#pragma unroll
    for (int t = 0; t < TPW; ++t) acc[t] = (f32x4){0.f, 0.f, 0.f, 0.f};

    const int nbase = c2_0 + ns * SLW + lrow;
#pragma unroll
    for (int ks = 0; ks < KST; ++ks) {
        bf16x8 a = *(const bf16x8*)&hl[mt * 16 + lrow][ks * 32 + quad * 8];
#pragma unroll
        for (int t = 0; t < TPW; ++t) {
            bf16x8 bfr = *(const bf16x8*)&w2t[(size_t)(nbase + t * 16) * CIN + ks * 32 + quad * 8];
            acc[t] = __builtin_amdgcn_mfma_f32_16x16x32_bf16(a, bfr, acc[t], 0, 0, 0);
        }
    }

#pragma unroll
    for (int t = 0; t < TPW; ++t) {
        float bias = b2[nbase + t * 16];
        float s = 0.f, sq = 0.f, amx = -3.4e38f, amn = 3.4e38f;
#pragma unroll
        for (int r = 0; r < 4; ++r) {
            float v = acc[t][r] + bias;
            s += v; sq += v * v;
            amx = fmaxf(amx, v); amn = fminf(amn, v);
        }
#pragma unroll
        for (int off = 16; off < 64; off <<= 1) {
            s += __shfl_xor(s, off);
            sq += __shfl_xor(sq, off);
            amx = fmaxf(amx, __shfl_xor(amx, off));
            amn = fminf(amn, __shfl_xor(amn, off));
        }
        if (quad == 0) {
            int lc = t * 16 + lrow;
            red[0][w][lc] = s; red[1][w][lc] = sq;
            red[2][w][lc] = amx; red[3][w][lc] = amn;
        }
    }
    __syncthreads();
    for (int c = tid; c < COUTB; c += 512) {
        int ns2 = c / SLW, lc = c % SLW;
        float s = 0.f, sq = 0.f, amx = -3.4e38f, amn = 3.4e38f;
#pragma unroll
        for (int m2 = 0; m2 < MT; ++m2) {
            int w2 = ns2 * MT + m2;
            s += red[0][w2][lc]; sq += red[1][w2][lc];
            amx = fmaxf(amx, red[2][w2][lc]);
            amn = fminf(amn, red[3][w2][lc]);
        }
        int slot = blockIdx.x & (SLOTS2 - 1);
        atomicAdd(&st2[(size_t)(slot * 2 + 0) * coutFull + c2_0 + c], s);
        atomicAdd(&st2[(size_t)(slot * 2 + 1) * coutFull + c2_0 + c], sq);
        mx[(size_t)bs * coutFull + c2_0 + c] = amx;
        mn[(size_t)bs * coutFull + c2_0 + c] = amn;
    }
}

// ---------------- apply body ----------------
__device__ __forceinline__ void apply_body(char* smraw, int blk, int nblk,
        const float* __restrict__ st2, int C, float cnt,
        const float* __restrict__ g2, const float* __restrict__ be2,
        const float* __restrict__ mx, const float* __restrict__ mn,
        int S, float* __restrict__ outT, int total, float* __restrict__ zero48)
{
    float* sc = (float*)smraw;
    float* sh = sc + 512;
    for (int c = threadIdx.x; c < C; c += 512) {
        float s0 = 0.f, s1 = 0.f;
        for (int sl = 0; sl < SLOTS2; ++sl) {
            s0 += st2[(size_t)(sl * 2 + 0) * C + c];
            s1 += st2[(size_t)(sl * 2 + 1) * C + c];
        }
        float mean = s0 / cnt;
        float var = s1 / cnt - mean * mean;
        float inv = 1.0f / sqrtf(var + EPSB);
        float scl = g2[c] * inv;
        sc[c] = scl; sh[c] = be2[c] - scl * mean;
    }
    __syncthreads();
    if (zero48 && blk == 0 && threadIdx.x < 48) zero48[threadIdx.x] = 0.f;
    for (int e = blk * 512 + threadIdx.x; e < total; e += nblk * 512) {
        int s = e % S;
        int rem = e / S;
        int c = rem % C;
        int b = rem / C;
        float scl = sc[c];
        size_t mi = (size_t)(b * S + s) * C + c;
        float v = (scl >= 0.f) ? mx[mi] : mn[mi];   // maxpool commutes through monotone BN
        outT[e] = fmaxf(scl * v + sh[c], 0.f);
    }
}

// ---------------- proj body: [xyz, BN2(mx/mn) feat] · W + bias (+opt SA3 stats) -------
template<int COUTB, bool DOSTATS>
__device__ __forceinline__ void proj_body(char* smraw, int blk,
        const float* __restrict__ xyzsrc,
        const float* __restrict__ mxF, const float* __restrict__ mnF,
        const float* __restrict__ stF, const float* __restrict__ gF,
        const float* __restrict__ beF, float cntF,
        int N, int CF, const float* __restrict__ W, int coutFull,
        const float* __restrict__ bias, float* __restrict__ outp,
        float* __restrict__ st3)
{
    constexpr int BK = 32, BKP = 36, TK = 4, TC = 4, THREADS = 512, ROWS = 64;
    constexpr int C2G = COUTB / TC;
    float (*al)[BKP] = (float (*)[BKP])smraw;
    float (*wl)[BKP] = (float (*)[BKP])(smraw + ROWS * BKP * 4);
    float* scF = (float*)(smraw + (ROWS + COUTB) * BKP * 4);
    float* shF = scF + CF;
    float* red2 = shF + CF;
    const int NCH = coutFull / COUTB;
    const int chunk = blk % NCH;
    const int rb = blk / NCH;
    const int m0 = rb * ROWS;
    const int c2_0 = chunk * COUTB;
    const int K = CF + 3;
    const int tid = threadIdx.x;
    const int c2g = tid % C2G, kt = tid / C2G;

    for (int c = tid; c < CF; c += THREADS) {
        float s0 = 0.f, s1 = 0.f;
        for (int sl = 0; sl < SLOTS2; ++sl) {
            s0 += stF[(size_t)(sl * 2 + 0) * CF + c];
            s1 += stF[(size_t)(sl * 2 + 1) * CF + c];
        }
        float mean = s0 / cntF;
        float var = s1 / cntF - mean * mean;
        float inv = 1.0f / sqrtf(var + EPSB);
        float scl = gF[c] * inv;
        scF[c] = scl; shF[c] = beF[c] - scl * mean;
    }

    float acc[TK][TC];
#pragma unroll
    for (int i = 0; i < TK; ++i)
#pragma unroll
        for (int j = 0; j < TC; ++j) acc[i][j] = 0.f;
    const int npan = (K + BK - 1) / BK;
    for (int pan = 0; pan < npan; ++pan) {
        __syncthreads();
        const int cbase = pan * BK;
        for (int e = tid; e < ROWS * BK; e += THREADS) {
            int rl = e / BK, cl = e % BK;
            int c = cbase + cl;
            int m = m0 + rl;
            float v = 0.f;
            if (c < 3) v = xyzsrc[(size_t)m * 3 + c];
            else if (c < K) {
                int cf = c - 3;
                float scl = scF[cf];
                size_t mi = (size_t)m * CF + cf;
                float pick = (scl >= 0.f) ? mxF[mi] : mnF[mi];
                v = fmaxf(scl * pick + shF[cf], 0.f);
            }
            al[rl][cl] = v;
        }
        for (int e = tid; e < COUTB * BK; e += THREADS) {
            int c2 = e % COUTB, cl = e / COUTB;
            int c = cbase + cl;
            wl[c2][cl] = (c < K) ? W[(size_t)c * coutFull + c2_0 + c2] : 0.f;
        }
        __syncthreads();
#pragma unroll
        for (int cl = 0; cl < BK; cl += 4) {
            float4 av[TK], wv[TC];
#pragma unroll
            for (int i = 0; i < TK; ++i) av[i] = *(const float4*)&al[kt * TK + i][cl];
#pragma unroll
            for (int j = 0; j < TC; ++j) wv[j] = *(const float4*)&wl[c2g + j * C2G][cl];
#pragma unroll
            for (int i = 0; i < TK; ++i)
#pragma unroll
                for (int j = 0; j < TC; ++j)
                    acc[i][j] += av[i].x * wv[j].x + av[i].y * wv[j].y
                               + av[i].z * wv[j].z + av[i].w * wv[j].w;
        }
    }
    float ps[TC], pq[TC];
#pragma unroll
    for (int j = 0; j < TC; ++j) {
        float bb_ = bias[c2_0 + c2g + j * C2G];
        float s = 0.f, sq = 0.f;
#pragma unroll
        for (int i = 0; i < TK; ++i) {
            int m = m0 + kt * TK + i;
            float v = acc[i][j] + bb_;
            outp[(size_t)m * coutFull + c2_0 + c2g + j * C2G] = v;
            s += v; sq += v * v;
        }
        ps[j] = s; pq[j] = sq;
    }
    if constexpr (DOSTATS) {
        const int w = tid >> 6, lane = tid & 63;
#pragma unroll
        for (int j = 0; j < TC; ++j) {
            ps[j] += __shfl_xor(ps[j], 32);
            pq[j] += __shfl_xor(pq[j], 32);
            if (lane < 32) {
                int c2 = c2g + j * C2G;
                red2[(w * COUTB + c2) * 2 + 0] = ps[j];
                red2[(w * COUTB + c2) * 2 + 1] = pq[j];
            }
        }
        __syncthreads();
        for (int c = tid; c < COUTB; c += THREADS) {
            float s = 0.f, sq = 0.f;
#pragma unroll
            for (int w2 = 0; w2 < 8; ++w2) {
                s += red2[(w2 * COUTB + c) * 2 + 0];
                sq += red2[(w2 * COUTB + c) * 2 + 1];
            }
            int slot = blk & (SLOTS1 - 1);
            atomicAdd(&st3[(size_t)(slot * 2 + 0) * coutFull + c2_0 + c], s);
            atomicAdd(&st3[(size_t)(slot * 2 + 1) * coutFull + c2_0 + c], sq);
        }
    }
}

// ---------------- Fused apply + proj launches ----------------
template<bool DOSTATS>
__global__ __launch_bounds__(512, 2)
void applyproj_kernel(
        const float* __restrict__ xyzsrc,
        const float* __restrict__ mxF, const float* __restrict__ mnF,
        const float* __restrict__ stF, const float* __restrict__ gF,
        const float* __restrict__ beF, float cntF,
        int Nrows, int CF, const float* __restrict__ W, int coutFull,
        const float* __restrict__ bias, float* __restrict__ outp,
        float* __restrict__ st3, int projBlocks,
        const float* __restrict__ st2, int C, float m2cnt,
        const float* __restrict__ g2, const float* __restrict__ be2,
        const float* __restrict__ mxA, const float* __restrict__ mnA,
        int S, float* __restrict__ outT, int total)
{
    __shared__ __attribute__((aligned(16))) char arena[38144];
    if ((int)blockIdx.x < projBlocks)
        proj_body<128, DOSTATS>(arena, blockIdx.x, xyzsrc, mxF, mnF, stF, gF, beF, cntF,
                                Nrows, CF, W, coutFull, bias, outp, st3);
    else
        apply_body(arena, blockIdx.x - projBlocks, gridDim.x - projBlocks,
                   st2, C, m2cnt, g2, be2, mxA, mnA, S, outT, total, nullptr);
}

__global__ __launch_bounds__(512, 2)
void apply3_kernel(const float* __restrict__ st2, int C, float cnt,
                   const float* __restrict__ g2, const float* __restrict__ be2,
                   const float* __restrict__ mx, const float* __restrict__ mn,
                   int S, float* __restrict__ outT, int total, float* __restrict__ zero48)
{
    __shared__ __attribute__((aligned(16))) char arena[4160];
    apply_body(arena, blockIdx.x, gridDim.x, st2, C, cnt, g2, be2, mx, mn, S, outT, total, zero48);
}

extern "C" void kernel_launch(void* const* d_in, const int* in_sizes, int n_in,
                              void* d_out, int out_size, void* d_ws, size_t ws_size,
                              hipStream_t stream)
{
    (void)in_sizes; (void)n_in; (void)out_size; (void)ws_size;
    const float* l0_xyz = (const float*)d_in[0];
    const float* l0_pts = (const float*)d_in[1];
    const float* w11 = (const float*)d_in[2];  const float* b11 = (const float*)d_in[3];
    const float* g11 = (const float*)d_in[4];  const float* be11 = (const float*)d_in[5];
    const float* w12 = (const float*)d_in[6];  const float* b12 = (const float*)d_in[7];
    const float* g12 = (const float*)d_in[8];  const float* be12 = (const float*)d_in[9];
    const float* w21 = (const float*)d_in[10]; const float* b21 = (const float*)d_in[11];
    const float* g21 = (const float*)d_in[12]; const float* be21 = (const float*)d_in[13];
    const float* w22 = (const float*)d_in[14]; const float* b22 = (const float*)d_in[15];
    const float* g22 = (const float*)d_in[16]; const float* be22 = (const float*)d_in[17];
    const float* w31 = (const float*)d_in[18]; const float* b31 = (const float*)d_in[19];
    const float* g31 = (const float*)d_in[20]; const float* be31 = (const float*)d_in[21];
    const float* w32 = (const float*)d_in[22]; const float* b32 = (const float*)d_in[23];
    const float* g32 = (const float*)d_in[24]; const float* be32 = (const float*)d_in[25];

    float* out = (float*)d_out;
    float* o_l1xyz = out;                 // (16,3,256)
    float* o_l1pts = out + 12288;         // (16,128,256)
    float* o_l2xyz = out + 536576;        // (16,3,128)
    float* o_l2pts = out + 542720;        // (16,256,128)
    float* o_l3xyz = out + 1067008;       // (16,3,1)
    float* o_x     = out + 1067056;       // (16,512)

    char* ws = (char*)d_ws;
    size_t off = 0;
    auto alloc = [&](size_t bytes) {
        void* r = ws + off;
        off += ((bytes + 255) & ~(size_t)255);
        return r;
    };
    float* nxyz1 = (float*)alloc(12288 * 4);
    float* nxyz2 = (float*)alloc(6144 * 4);
    int*   gi1   = (int*)alloc(131072 * 4);
    int*   gi2   = (int*)alloc(131072 * 4);
    float* p1    = (float*)alloc(4194304 * 4);
    float* q1    = (float*)alloc(262144 * 4);
    float* mx1   = (float*)alloc(524288 * 4);
    float* mn1   = (float*)alloc(524288 * 4);
    float* p2    = (float*)alloc(524288 * 4);
    float* q2    = (float*)alloc(262144 * 4);
    float* mx2   = (float*)alloc(524288 * 4);
    float* mn2   = (float*)alloc(524288 * 4);
    float* h31   = (float*)alloc(524288 * 4);
    float* mx3   = (float*)alloc(8192 * 4);
    float* mn3   = (float*)alloc(8192 * 4);
    float* stats = (float*)alloc(129024 * 4);
    float* st1a = stats;                 // 16*2*64
    float* st2a = st1a + 2048;           // 64*2*128
    float* st1b = st2a + 16384;          // 16*2*128
    float* st2b = st1b + 4096;           // 64*2*256
    float* st3a = st2b + 32768;          // 16*2*256
    float* st3b = st3a + 8192;           // 64*2*512
    unsigned short* w12t = (unsigned short*)alloc(128 * 64 * 2);
    unsigned short* w22t = (unsigned short*)alloc(256 * 128 * 2);
    unsigned short* w32t = (unsigned short*)alloc(512 * 256 * 2);

    // L1: fps1 + project6 + weight transposes + stats zero (1024-thread blocks)
    mega1_kernel<<<4406, 1024, 0, stream>>>(l0_xyz, l0_pts, w11, b11, p1,
                                            nxyz1, o_l1xyz,
                                            w12, w12t, w22, w22t, w32, w32t, stats);
    // L2: fps2 (16 waves) + ballquery/stats SA1 (4096 waves) @ 4 waves/block
    ballstat_kernel<32, 64, true><<<1028, 256, 0, stream>>>(
        l0_xyz, 3 * 4096, 4096, 1, 4096, nxyz1, 256, 0.04f, gi1, w11, q1, p1, st1a,
        nxyz1, nxyz2, o_l2xyz);
    // L3: SA1 layer2 MFMA (+BN1 finalize inline)
    mfma_gemm_kernel<32, 64, 128><<<4096, 512, 0, stream>>>(
        p1, q1, gi1, 256, 1, 4096, st1a, 131072.0f, g11, be11, w12t, 128, b12,
        st2a, mx1, mn1);
    // L4: proj2 (64 blocks, feat1 on the fly) + apply1 (64 blocks -> o_l1pts)
    applyproj_kernel<false><<<128, 512, 0, stream>>>(
        nxyz1, mx1, mn1, st2a, g12, be12, 131072.0f, 256, 128, w21, 128, b21, p2,
        nullptr, 64,
        st2a, 128, 131072.0f, g12, be12, mx1, mn1, 256, o_l1pts, 524288);
    // L5: ballquery/stats SA2 @ 4 waves/block
    ballstat_kernel<64, 128, false><<<512, 256, 0, stream>>>(
        nxyz1, 768, 1, 3, 256, nxyz2, 128, 0.0625f, gi2, w21, q2, p2, st1b,
        nullptr, nullptr, nullptr);
    // L6: SA2 layer2 MFMA
    mfma_gemm_kernel<64, 128, 256><<<2048, 512, 0, stream>>>(
        p2, q2, gi2, 128, 1, 256, st1b, 131072.0f, g21, be21, w22t, 256, b22,
        st2b, mx2, mn2);
    // L7: proj3 (64 blocks, feat2 on the fly, + SA3 BN1 stats) + apply2 (64 blocks)
    applyproj_kernel<true><<<128, 512, 0, stream>>>(
        nxyz2, mx2, mn2, st2b, g22, be22, 131072.0f, 128, 256, w31, 256, b31, h31,
        st3a, 64,
        st2b, 256, 131072.0f, g22, be22, mx2, mn2, 128, o_l2pts, 524288);
    // L8: SA3 layer2 MFMA
    mfma_gemm_kernel<128, 256, 128><<<64, 512, 0, stream>>>(
        h31, nullptr, nullptr, 1, 4, 0, st3a, 2048.0f, g31, be31, w32t, 512, b32,
        st3b, mx3, mn3);
    // L9: final apply -> o_x, zero o_l3xyz
    apply3_kernel<<<16, 512, 0, stream>>>(st3b, 512, 2048.0f, g32, be32, mx3, mn3,
                                          1, o_x, 8192, o_l3xyz);
}

// Round 10
// 562.287 us; speedup vs baseline: 1.1205x; 1.1205x over previous
//
#include <hip/hip_runtime.h>
#include <cstddef>

// PointNet++ set-abstraction pipeline (B=16, N=4096, HC=64).
// R10: back to the R6 structure (best: 528us). FPS inner loop now reads packed
// float4 coords from LDS (1x ds_read_b128/point) instead of 3x ds_read_b32
// remat — the fps is LDS-issue bound, so instruction count is the lever.
// No register coord arrays in the multi-wave path (the allocator spilled them
// in R6/R7/R9 no matter what); dist[] stays in regs (proven resident).

#define EPSB 1e-5f
constexpr int SLOTS1 = 16;
constexpr int SLOTS2 = 64;

static __device__ __forceinline__ unsigned long long umax64(unsigned long long a,
                                                            unsigned long long b)
{
    return a > b ? a : b;
}

static __device__ __forceinline__ unsigned pack_bf16x2(float a, float b)
{
    unsigned ua = __float_as_uint(a), ub = __float_as_uint(b);
    ua += 0x7fffu + ((ua >> 16) & 1u);
    ub += 0x7fffu + ((ub >> 16) & 1u);
    return (ua >> 16) | (ub & 0xffff0000u);
}

static __device__ __forceinline__ unsigned short bf16_of(float a)
{
    unsigned u = __float_as_uint(a);
    u += 0x7fffu + ((u >> 16) & 1u);
    return (unsigned short)(u >> 16);
}

// Full-wave u64 max via DPP (row_shr 1/2/4/8 + row_bcast15/31), broadcast to
// all lanes via readlane 63. All 64 lanes must be active.
static __device__ __forceinline__ unsigned long long wave_umax64_dpp(unsigned long long x)
{
#define DPP_STEP(ctrl, rmask)                                                        \
    {                                                                                \
        int lo_ = __builtin_amdgcn_update_dpp(0, (int)(unsigned)x, ctrl, rmask, 0xf, false); \
        int hi_ = __builtin_amdgcn_update_dpp(0, (int)(unsigned)(x >> 32), ctrl, rmask, 0xf, false); \
        unsigned long long c_ = ((unsigned long long)(unsigned)hi_ << 32) | (unsigned)lo_; \
        x = umax64(x, c_);                                                           \
    }
    DPP_STEP(0x111, 0xf)
    DPP_STEP(0x112, 0xf)
    DPP_STEP(0x114, 0xf)
    DPP_STEP(0x118, 0xf)
    DPP_STEP(0x142, 0xa)
    DPP_STEP(0x143, 0xc)
#undef DPP_STEP
    unsigned lo = (unsigned)__builtin_amdgcn_readlane((int)(unsigned)x, 63);
    unsigned hi = (unsigned)__builtin_amdgcn_readlane((int)(unsigned)(x >> 32), 63);
    return ((unsigned long long)hi << 32) | lo;
}

// ---------------- FPS body ----------------
// jax scan semantics: idx[0]=0; dist=min(dist,|x-c|^2); next=argmax (first-index
// ties). Key: hi = dist bits (>=0), lo = ~gidx (max -> smallest index).
// NW>1: coords live ONLY in the float4 LDS mirror; dist loop does one
// ds_read_b128 per point per round. NW==1: register coords + readlane.
template<int N, int NPOINT, int THREADS>
__device__ __forceinline__ void fps_body(int t,
        float4* cmir, unsigned long long* kslots,
        const float* __restrict__ xyz, int bStride, int cStride, int nStride,
        int b, float* __restrict__ nxyz, float* __restrict__ lxyz)
{
    constexpr int PT = N / THREADS;
    constexpr int NW = THREADS / 64;
    constexpr int NSTASH = (NPOINT + THREADS - 1) / THREADS;
    const float* xb = xyz + (size_t)b * bStride;

    float stx[NSTASH], sty[NSTASH], stz[NSTASH];
#pragma unroll
    for (int i = 0; i < NSTASH; ++i) { stx[i] = 0.f; sty[i] = 0.f; stz[i] = 0.f; }

    if constexpr (NW > 1) {
        float dist[PT];
#pragma unroll
        for (int i = 0; i < PT; ++i) {
            int p = t + i * THREADS;
            float x = xb[(size_t)0 * cStride + (size_t)p * nStride];
            float y = xb[(size_t)1 * cStride + (size_t)p * nStride];
            float z = xb[(size_t)2 * cStride + (size_t)p * nStride];
            cmir[p] = make_float4(x, y, z, 0.f);
            dist[i] = 1e10f;
        }
        float cx = xb[0], cy = xb[(size_t)cStride], cz = xb[(size_t)2 * cStride];
        if (t == 0) { stx[0] = cx; sty[0] = cy; stz[0] = cz; }
        __syncthreads();   // mirror ready

        for (int it = 1; it < NPOINT; ++it) {
            float bv = -1.0f; int bidx = 0;
#pragma unroll
            for (int i = 0; i < PT; ++i) {
                float4 c4 = cmir[t + i * THREADS];   // one ds_read_b128
                float dx = c4.x - cx, dy = c4.y - cy, dz = c4.z - cz;
                float d = __builtin_fmaf(dx, dx, __builtin_fmaf(dy, dy, dz * dz));
                float nd = fminf(dist[i], d);
                dist[i] = nd;
                bool g = nd > bv;      // strict >: keeps lowest index within lane
                bv = g ? nd : bv;
                bidx = g ? (t + i * THREADS) : bidx;
            }
            unsigned long long best =
                ((unsigned long long)__float_as_uint(bv) << 32) | (unsigned)(~bidx);
            best = wave_umax64_dpp(best);
            const int pb = it & 1;
            if ((t & 63) == 0) kslots[pb * NW + (t >> 6)] = best;
            __syncthreads();
            const ulonglong2* kp = (const ulonglong2*)(kslots + pb * NW);
            unsigned long long m = best;
#pragma unroll
            for (int w2 = 0; w2 < NW / 2; ++w2) {   // broadcast reads (same addr)
                ulonglong2 kk = kp[w2];
                m = umax64(m, umax64(kk.x, kk.y));
            }
            int widx = (int)(~(unsigned)m);
            float4 c = cmir[widx];   // single broadcast ds_read_b128
            cx = c.x; cy = c.y; cz = c.z;
            if constexpr (NSTASH == 1) {
                if (t == it) { stx[0] = cx; sty[0] = cy; stz[0] = cz; }
            } else {
                if ((it & (THREADS - 1)) == t) {
                    if (it >= THREADS) { stx[1] = cx; sty[1] = cy; stz[1] = cz; }
                    else               { stx[0] = cx; sty[0] = cy; stz[0] = cz; }
                }
            }
        }
    } else {
        float px[PT], py[PT], pz[PT], dist[PT];
#pragma unroll
        for (int i = 0; i < PT; ++i) {
            int p = t + i * THREADS;
            px[i] = xb[(size_t)0 * cStride + (size_t)p * nStride];
            py[i] = xb[(size_t)1 * cStride + (size_t)p * nStride];
            pz[i] = xb[(size_t)2 * cStride + (size_t)p * nStride];
            dist[i] = 1e10f;
        }
        float cx = xb[0], cy = xb[(size_t)cStride], cz = xb[(size_t)2 * cStride];
        if (t == 0) { stx[0] = cx; sty[0] = cy; stz[0] = cz; }

        for (int it = 1; it < NPOINT; ++it) {
            float bv = -1.0f; int bidx = 0;
            float bx = 0.f, by = 0.f, bz = 0.f;
#pragma unroll
            for (int i = 0; i < PT; ++i) {
                float dx = px[i] - cx, dy = py[i] - cy, dz = pz[i] - cz;
                float d = __builtin_fmaf(dx, dx, __builtin_fmaf(dy, dy, dz * dz));
                float nd = fminf(dist[i], d);
                dist[i] = nd;
                bool g = nd > bv;
                bv = g ? nd : bv;
                bidx = g ? (t + i * THREADS) : bidx;
                bx = g ? px[i] : bx; by = g ? py[i] : by; bz = g ? pz[i] : bz;
            }
            unsigned long long mykey =
                ((unsigned long long)__float_as_uint(bv) << 32) | (unsigned)(~bidx);
            unsigned long long wkey = wave_umax64_dpp(mykey);
            unsigned long long ball = __ballot(mykey == wkey);
            int wl = __ffsll(ball) - 1;   // uniform winner lane
            cx = __int_as_float(__builtin_amdgcn_readlane(__float_as_int(bx), wl));
            cy = __int_as_float(__builtin_amdgcn_readlane(__float_as_int(by), wl));
            cz = __int_as_float(__builtin_amdgcn_readlane(__float_as_int(bz), wl));
            if constexpr (NSTASH == 1) {
                if (t == it) { stx[0] = cx; sty[0] = cy; stz[0] = cz; }
            } else {
                if ((it & (THREADS - 1)) == t) {
                    if (it >= THREADS) { stx[1] = cx; sty[1] = cy; stz[1] = cz; }
                    else               { stx[0] = cx; sty[0] = cy; stz[0] = cz; }
                }
            }
        }
    }
#pragma unroll
    for (int s2 = 0; s2 < NSTASH; ++s2) {
        int s = t + s2 * THREADS;
        if (s < NPOINT) {
            nxyz[(size_t)(b * NPOINT + s) * 3 + 0] = stx[s2];
            nxyz[(size_t)(b * NPOINT + s) * 3 + 1] = sty[s2];
            nxyz[(size_t)(b * NPOINT + s) * 3 + 2] = stz[s2];
            lxyz[(size_t)b * 3 * NPOINT + 0 * NPOINT + s] = stx[s2];
            lxyz[(size_t)b * 3 * NPOINT + 1 * NPOINT + s] = sty[s2];
            lxyz[(size_t)b * 3 * NPOINT + 2 * NPOINT + s] = stz[s2];
        }
    }
}

// ---------------- Mega-kernel 1: fps1 + project6 + w2t x3 + stats-zero ----------------
__global__ __launch_bounds__(512)
void mega1_kernel(const float* __restrict__ l0_xyz, const float* __restrict__ l0_pts,
                  const float* __restrict__ w11, const float* __restrict__ b11,
                  float* __restrict__ p1,
                  float* __restrict__ nxyz1, float* __restrict__ o_l1xyz,
                  const float* __restrict__ w12, unsigned short* __restrict__ w12t,
                  const float* __restrict__ w22, unsigned short* __restrict__ w22t,
                  const float* __restrict__ w32, unsigned short* __restrict__ w32t,
                  float* __restrict__ stats)
{
    __shared__ __attribute__((aligned(16))) float4 cmir[4096];
    __shared__ __attribute__((aligned(16))) unsigned long long kxs[16];
    int blk = blockIdx.x;
    const int tid = threadIdx.x;
    if (blk < 16) {
        fps_body<4096, 256, 512>(tid, cmir, kxs,
                                 l0_xyz, 3 * 4096, 4096, 1, blk, nxyz1, o_l1xyz);
        return;
    }
    blk -= 16;
    if (blk < 8192) {  // project6: p1[b,n,64] = [xyz,pts]·W1 + b1
        int idx = blk * 512 + tid;
        int d = idx & 63;
        int n = (idx >> 6) & 4095;
        int b = idx >> 18;
        const float* xb = l0_xyz + (size_t)b * 3 * 4096 + n;
        const float* pb = l0_pts + (size_t)b * 3 * 4096 + n;
        float a0 = xb[0], a1 = xb[4096], a2 = xb[2 * 4096];
        float a3 = pb[0], a4 = pb[4096], a5 = pb[2 * 4096];
        float acc = b11[d];
        acc += a0 * w11[d] + a1 * w11[64 + d] + a2 * w11[128 + d];
        acc += a3 * w11[192 + d] + a4 * w11[256 + d] + a5 * w11[320 + d];
        p1[idx] = acc;
        return;
    }
    blk -= 8192;
    if (blk < 16) {
        int i = blk * 512 + tid;
        if (i < 64 * 128) { int k = i / 128, n = i % 128; w12t[(size_t)n * 64 + k] = bf16_of(w12[i]); }
        return;
    }
    blk -= 16;
    if (blk < 64) {
        int i = blk * 512 + tid;
        if (i < 128 * 256) { int k = i / 256, n = i % 256; w22t[(size_t)n * 128 + k] = bf16_of(w22[i]); }
        return;
    }
    blk -= 64;
    if (blk < 256) {
        int i = blk * 512 + tid;
        if (i < 256 * 512) { int k = i / 512, n = i % 512; w32t[(size_t)n * 256 + k] = bf16_of(w32[i]); }
        return;
    }
    blk -= 256;
    {
        int i = blk * 512 + tid;
        if (i < 129024) stats[i] = 0.f;
    }
}

// ---------------- Ball query + q projection + fused BN1 stats (+opt fps2) -------------
// 256 threads = 4 waves; one ball per wave.
template<int NS, int D, bool WITHFPS>
__global__ __launch_bounds__(256)
void ballstat_kernel(const float* __restrict__ xyz, int bStride, int cStride, int nStride, int N,
                     const float* __restrict__ nxyz, int S, float r2,
                     int* __restrict__ gi,
                     const float* __restrict__ W, float* __restrict__ q,
                     const float* __restrict__ p, float* __restrict__ slots,
                     const float* __restrict__ fxyz, float* __restrict__ fnxyz,
                     float* __restrict__ flxyz)
{
    __shared__ int sgo[4][NS];
    const int wid = threadIdx.x >> 6, l = threadIdx.x & 63;
    int g = blockIdx.x * 4 + wid;
    if constexpr (WITHFPS) {
        if (g < 16) {
            fps_body<256, 128, 64>(l, nullptr, nullptr,
                                   fxyz, 768, 1, 3, g, fnxyz, flxyz);
            return;
        }
        g -= 16;
    }
    constexpr int DL = D / 64;
    const int bs = g;
    const int b = bs / S;
    float cx = nxyz[(size_t)bs * 3 + 0], cy = nxyz[(size_t)bs * 3 + 1], cz = nxyz[(size_t)bs * 3 + 2];
    float s2 = cx * cx + cy * cy + cz * cz;
    const float* xb = xyz + (size_t)b * bStride;
    int cnt = 0;
    int first = N - 1;
    int* go = gi + (size_t)bs * NS;
    for (int base = 0; base < N; base += 64) {
        int n = base + l;
        float x = xb[(size_t)0 * cStride + (size_t)n * nStride];
        float y = xb[(size_t)1 * cStride + (size_t)n * nStride];
        float z = xb[(size_t)2 * cStride + (size_t)n * nStride];
        float x2 = x * x + y * y + z * z;
        float dot = cx * x + cy * y + cz * z;
        float sqr = (s2 + x2) - 2.0f * dot;   // reference expansion form
        bool pass = (sqr <= r2);
        unsigned long long m = __ballot(pass);
        if (cnt == 0 && m) first = base + (__ffsll((unsigned long long)m) - 1);
        int pos = cnt + __popcll(m & ((1ull << l) - 1ull));
        if (pass && pos < NS) { go[pos] = n; sgo[wid][pos] = n; }
        cnt += __popcll(m);
        if (cnt >= NS) break;
    }
    if (cnt < NS && l >= cnt && l < NS) { go[l] = first; sgo[wid][l] = first; }

    float qv[DL];
#pragma unroll
    for (int j = 0; j < DL; ++j) {
        int d = j * 64 + l;
        qv[j] = cx * W[d] + cy * W[D + d] + cz * W[2 * D + d];
        q[(size_t)bs * D + d] = qv[j];
    }
    float s[DL], ss[DL];
#pragma unroll
    for (int j = 0; j < DL; ++j) { s[j] = 0.f; ss[j] = 0.f; }
#pragma unroll 4
    for (int k = 0; k < NS; ++k) {
        int idx = sgo[wid][k];
        const float* pr = p + (size_t)(b * N + idx) * D;
#pragma unroll
        for (int j = 0; j < DL; ++j) {
            float v = pr[j * 64 + l] - qv[j];
            s[j] += v; ss[j] += v * v;
        }
    }
    int slot = bs & (SLOTS1 - 1);
#pragma unroll
    for (int j = 0; j < DL; ++j) {
        int d = j * 64 + l;
        atomicAdd(&slots[(size_t)(slot * 2 + 0) * D + d], s[j]);
        atomicAdd(&slots[(size_t)(slot * 2 + 1) * D + d], ss[j]);
    }
}

// ---------------- MFMA layer-2 with inline BN1 finalize ----------------
template<int KS, int CIN, int COUTB>
__global__ __launch_bounds__(512, 2)
void mfma_gemm_kernel(const float* __restrict__ p, const float* __restrict__ q,
                      const int* __restrict__ gi, int S, int NCH, int N,
                      const float* __restrict__ st1, float m1cnt,
                      const float* __restrict__ g1, const float* __restrict__ be1,
                      const unsigned short* __restrict__ w2t, int coutFull,
                      const float* __restrict__ b2,
                      float* __restrict__ st2,
                      float* __restrict__ mx, float* __restrict__ mn)
{
    constexpr int MT = KS / 16;
    constexpr int NSL = 8 / MT;
    constexpr int SLW = COUTB / NSL;
    constexpr int TPW = SLW / 16;
    constexpr int KST = CIN / 32;
    constexpr int LDA = CIN + 8;
    typedef __attribute__((ext_vector_type(8))) short bf16x8;
    typedef __attribute__((ext_vector_type(4))) float f32x4;

    __shared__ __attribute__((aligned(16))) unsigned short hl[KS][LDA];
    __shared__ float red[4][8][SLW];
    __shared__ __attribute__((aligned(16))) float ss_scale[CIN];
    __shared__ __attribute__((aligned(16))) float ss_shift[CIN];

    const int chunk = blockIdx.x % NCH;
    const int bs = blockIdx.x / NCH;
    const int b = bs / S;
    const int tid = threadIdx.x;
    const int c2_0 = chunk * COUTB;
    const int w = tid >> 6, lane = tid & 63;
    const int mt = w % MT, ns = w / MT;
    const int lrow = lane & 15, quad = lane >> 4;

    for (int c = tid; c < CIN; c += 512) {
        float s0 = 0.f, s1 = 0.f;
        for (int sl = 0; sl < SLOTS1; ++sl) {
            s0 += st1[(size_t)(sl * 2 + 0) * CIN + c];
            s1 += st1[(size_t)(sl * 2 + 1) * CIN + c];
        }
        float mean = s0 / m1cnt;
        float var = s1 / m1cnt - mean * mean;
        float inv = 1.0f / sqrtf(var + EPSB);
        float scl = g1[c] * inv;
        ss_scale[c] = scl;
        ss_shift[c] = be1[c] - scl * mean;
    }
    __syncthreads();

    constexpr int ITER = KS * CIN / (512 * 4);
    const int gbase = bs * KS;
#pragma unroll
    for (int it = 0; it < ITER; ++it) {
        int e = (it * 512 + tid) * 4;
        int k = e / CIN, c = e % CIN;
        int row = gi ? (b * N + gi[gbase + k]) : (b * KS + k);
        float4 v = *(const float4*)&p[(size_t)row * CIN + c];
        if (q) {
            float4 qq = *(const float4*)&q[(size_t)bs * CIN + c];
            v.x -= qq.x; v.y -= qq.y; v.z -= qq.z; v.w -= qq.w;
        }
        float4 sc = *(const float4*)&ss_scale[c];
        float4 sh = *(const float4*)&ss_shift[c];
        v.x = fmaxf(__builtin_fmaf(sc.x, v.x, sh.x), 0.f);
        v.y = fmaxf(__builtin_fmaf(sc.y, v.y, sh.y), 0.f);
        v.z = fmaxf(__builtin_fmaf(sc.z, v.z, sh.z), 0.f);
        v.w = fmaxf(__builtin_fmaf(sc.w, v.w, sh.w), 0.f);
        uint2 pk;
        pk.x = pack_bf16x2(v.x, v.y);
        pk.y = pack_bf16x2(v.z, v.w);
        *(uint2*)&hl[k][c] = pk;
    }
    __syncthreads();

    f32x4 acc[TPW];
#pragma unroll
    for (int t = 0; t < TPW; ++t) acc[t] = (f32x4){0.f, 0.f, 0.f, 0.f};

    const int nbase = c2_0 + ns * SLW + lrow;
#pragma unroll
    for (int ks = 0; ks < KST; ++ks) {
        bf16x8 a = *(const bf16x8*)&hl[mt * 16 + lrow][ks * 32 + quad * 8];
#pragma unroll
        for (int t = 0; t < TPW; ++t) {
            bf16x8 bfr = *(const bf16x8*)&w2t[(size_t)(nbase + t * 16) * CIN + ks * 32 + quad * 8];
            acc[t] = __builtin_amdgcn_mfma_f32_16x16x32_bf16(a, bfr, acc[t], 0, 0, 0);
        }
    }

#pragma unroll
    for (int t = 0; t < TPW; ++t) {
        float bias = b2[nbase + t * 16];
        float s = 0.f, sq = 0.f, amx = -3.4e38f, amn = 3.4e38f;
#pragma unroll
        for (int r = 0; r < 4; ++r) {
            float v = acc[t][r] + bias;
            s += v; sq += v * v;
            amx = fmaxf(amx, v); amn = fminf(amn, v);
        }
#pragma unroll
        for (int off = 16; off < 64; off <<= 1) {
            s += __shfl_xor(s, off);
            sq += __shfl_xor(sq, off);
            amx = fmaxf(amx, __shfl_xor(amx, off));
            amn = fminf(amn, __shfl_xor(amn, off));
        }
        if (quad == 0) {
            int lc = t * 16 + lrow;
            red[0][w][lc] = s; red[1][w][lc] = sq;
            red[2][w][lc] = amx; red[3][w][lc] = amn;
        }
    }
    __syncthreads();
    for (int c = tid; c < COUTB; c += 512) {
        int ns2 = c / SLW, lc = c % SLW;
        float s = 0.f, sq = 0.f, amx = -3.4e38f, amn = 3.4e38f;
#pragma unroll
        for (int m2 = 0; m2 < MT; ++m2) {
            int w2 = ns2 * MT + m2;
            s += red[0][w2][lc]; sq += red[1][w2][lc];
            amx = fmaxf(amx, red[2][w2][lc]);
            amn = fminf(amn, red[3][w2][lc]);
        }
        int slot = blockIdx.x & (SLOTS2 - 1);
        atomicAdd(&st2[(size_t)(slot * 2 + 0) * coutFull + c2_0 + c], s);
        atomicAdd(&st2[(size_t)(slot * 2 + 1) * coutFull + c2_0 + c], sq);
        mx[(size_t)bs * coutFull + c2_0 + c] = amx;
        mn[(size_t)bs * coutFull + c2_0 + c] = amn;
    }
}

// ---------------- apply body ----------------
__device__ __forceinline__ void apply_body(char* smraw, int blk, int nblk,
        const float* __restrict__ st2, int C, float cnt,
        const float* __restrict__ g2, const float* __restrict__ be2,
        const float* __restrict__ mx, const float* __restrict__ mn,
        int S, float* __restrict__ outT, int total, float* __restrict__ zero48)
{
    float* sc = (float*)smraw;
    float* sh = sc + 512;
    for (int c = threadIdx.x; c < C; c += 512) {
        float s0 = 0.f, s1 = 0.f;
        for (int sl = 0; sl < SLOTS2; ++sl) {
            s0 += st2[(size_t)(sl * 2 + 0) * C + c];
            s1 += st2[(size_t)(sl * 2 + 1) * C + c];
        }
        float mean = s0 / cnt;
        float var = s1 / cnt - mean * mean;
        float inv = 1.0f / sqrtf(var + EPSB);
        float scl = g2[c] * inv;
        sc[c] = scl; sh[c] = be2[c] - scl * mean;
    }
    __syncthreads();
    if (zero48 && blk == 0 && threadIdx.x < 48) zero48[threadIdx.x] = 0.f;
    for (int e = blk * 512 + threadIdx.x; e < total; e += nblk * 512) {
        int s = e % S;
        int rem = e / S;
        int c = rem % C;
        int b = rem / C;
        float scl = sc[c];
        size_t mi = (size_t)(b * S + s) * C + c;
        float v = (scl >= 0.f) ? mx[mi] : mn[mi];   // maxpool commutes through monotone BN
        outT[e] = fmaxf(scl * v + sh[c], 0.f);
    }
}

// ---------------- proj body: [xyz, BN2(mx/mn) feat] · W + bias (+opt SA3 stats) -------
template<int COUTB, bool DOSTATS>
__device__ __forceinline__ void proj_body(char* smraw, int blk,
        const float* __restrict__ xyzsrc,
        const float* __restrict__ mxF, const float* __restrict__ mnF,
        const float* __restrict__ stF, const float* __restrict__ gF,
        const float* __restrict__ beF, float cntF,
        int N, int CF, const float* __restrict__ W, int coutFull,
        const float* __restrict__ bias, float* __restrict__ outp,
        float* __restrict__ st3)
{
    constexpr int BK = 32, BKP = 36, TK = 4, TC = 4, THREADS = 512, ROWS = 64;
    constexpr int C2G = COUTB / TC;
    float (*al)[BKP] = (float (*)[BKP])smraw;
    float (*wl)[BKP] = (float (*)[BKP])(smraw + ROWS * BKP * 4);
    float* scF = (float*)(smraw + (ROWS + COUTB) * BKP * 4);
    float* shF = scF + CF;
    float* red2 = shF + CF;
    const int NCH = coutFull / COUTB;
    const int chunk = blk % NCH;
    const int rb = blk / NCH;
    const int m0 = rb * ROWS;
    const int c2_0 = chunk * COUTB;
    const int K = CF + 3;
    const int tid = threadIdx.x;
    const int c2g = tid % C2G, kt = tid / C2G;

    for (int c = tid; c < CF; c += THREADS) {
        float s0 = 0.f, s1 = 0.f;
        for (int sl = 0; sl < SLOTS2; ++sl) {
            s0 += stF[(size_t)(sl * 2 + 0) * CF + c];
            s1 += stF[(size_t)(sl * 2 + 1) * CF + c];
        }
        float mean = s0 / cntF;
        float var = s1 / cntF - mean * mean;
        float inv = 1.0f / sqrtf(var + EPSB);
        float scl = gF[c] * inv;
        scF[c] = scl; shF[c] = beF[c] - scl * mean;
    }

    float acc[TK][TC];
#pragma unroll
    for (int i = 0; i < TK; ++i)
#pragma unroll
        for (int j = 0; j < TC; ++j) acc[i][j] = 0.f;
    const int npan = (K + BK - 1) / BK;
    for (int pan = 0; pan < npan; ++pan) {
        __syncthreads();
        const int cbase = pan * BK;
        for (int e = tid; e < ROWS * BK; e += THREADS) {
            int rl = e / BK, cl = e % BK;
            int c = cbase + cl;
            int m = m0 + rl;
            float v = 0.f;
            if (c < 3) v = xyzsrc[(size_t)m * 3 + c];
            else if (c < K) {
                int cf = c - 3;
                float scl = scF[cf];
                size_t mi = (size_t)m * CF + cf;
                float pick = (scl >= 0.f) ? mxF[mi] : mnF[mi];
                v = fmaxf(scl * pick + shF[cf], 0.f);
            }
            al[rl][cl] = v;
        }
        for (int e = tid; e < COUTB * BK; e += THREADS) {
            int c2 = e % COUTB, cl = e / COUTB;
            int c = cbase + cl;
            wl[c2][cl] = (c < K) ? W[(size_t)c * coutFull + c2_0 + c2] : 0.f;
        }
        __syncthreads();
#pragma unroll
        for (int cl = 0; cl < BK; cl += 4) {
            float4 av[TK], wv[TC];
#pragma unroll
            for (int i = 0; i < TK; ++i) av[i] = *(const float4*)&al[kt * TK + i][cl];
#pragma unroll
            for (int j = 0; j < TC; ++j) wv[j] = *(const float4*)&wl[c2g + j * C2G][cl];
#pragma unroll
            for (int i = 0; i < TK; ++i)
#pragma unroll
                for (int j = 0; j < TC; ++j)
                    acc[i][j] += av[i].x * wv[j].x + av[i].y * wv[j].y
                               + av[i].z * wv[j].z + av[i].w * wv[j].w;
        }
    }
    float ps[TC], pq[TC];
#pragma unroll
    for (int j = 0; j < TC; ++j) {
        float bb_ = bias[c2_0 + c2g + j * C2G];
        float s = 0.f, sq = 0.f;
#pragma unroll
        for (int i = 0; i < TK; ++i) {
            int m = m0 + kt * TK + i;
            float v = acc[i][j] + bb_;
            outp[(size_t)m * coutFull + c2_0 + c2g + j * C2G] = v;
            s += v; sq += v * v;
        }
        ps[j] = s; pq[j] = sq;
    }
    if constexpr (DOSTATS) {
        const int w = tid >> 6, lane = tid & 63;
#pragma unroll
        for (int j = 0; j < TC; ++j) {
            ps[j] += __shfl_xor(ps[j], 32);
            pq[j] += __shfl_xor(pq[j], 32);
            if (lane < 32) {
                int c2 = c2g + j * C2G;
                red2[(w * COUTB + c2) * 2 + 0] = ps[j];
                red2[(w * COUTB + c2) * 2 + 1] = pq[j];
            }
        }
        __syncthreads();
        for (int c = tid; c < COUTB; c += THREADS) {
            float s = 0.f, sq = 0.f;
#pragma unroll
            for (int w2 = 0; w2 < 8; ++w2) {
                s += red2[(w2 * COUTB + c) * 2 + 0];
                sq += red2[(w2 * COUTB + c) * 2 + 1];
            }
            int slot = blk & (SLOTS1 - 1);
            atomicAdd(&st3[(size_t)(slot * 2 + 0) * coutFull + c2_0 + c], s);
            atomicAdd(&st3[(size_t)(slot * 2 + 1) * coutFull + c2_0 + c], sq);
        }
    }
}

// ---------------- Fused apply + proj launches ----------------
template<bool DOSTATS>
__global__ __launch_bounds__(512, 2)
void applyproj_kernel(
        const float* __restrict__ xyzsrc,
        const float* __restrict__ mxF, const float* __restrict__ mnF,
        const float* __restrict__ stF, const float* __restrict__ gF,
        const float* __restrict__ beF, float cntF,
        int Nrows, int CF, const float* __restrict__ W, int coutFull,
        const float* __restrict__ bias, float* __restrict__ outp,
        float* __restrict__ st3, int projBlocks,
        const float* __restrict__ st2, int C, float m2cnt,
        const float* __restrict__ g2, const float* __restrict__ be2,
        const float* __restrict__ mxA, const float* __restrict__ mnA,
        int S, float* __restrict__ outT, int total)
{
    __shared__ __attribute__((aligned(16))) char arena[38144];
    if ((int)blockIdx.x < projBlocks)
        proj_body<128, DOSTATS>(arena, blockIdx.x, xyzsrc, mxF, mnF, stF, gF, beF, cntF,
                                Nrows, CF, W, coutFull, bias, outp, st3);
    else
        apply_body(arena, blockIdx.x - projBlocks, gridDim.x - projBlocks,
                   st2, C, m2cnt, g2, be2, mxA, mnA, S, outT, total, nullptr);
}

__global__ __launch_bounds__(512, 2)
void apply3_kernel(const float* __restrict__ st2, int C, float cnt,
                   const float* __restrict__ g2, const float* __restrict__ be2,
                   const float* __restrict__ mx, const float* __restrict__ mn,
                   int S, float* __restrict__ outT, int total, float* __restrict__ zero48)
{
    __shared__ __attribute__((aligned(16))) char arena[4160];
    apply_body(arena, blockIdx.x, gridDim.x, st2, C, cnt, g2, be2, mx, mn, S, outT, total, zero48);
}

extern "C" void kernel_launch(void* const* d_in, const int* in_sizes, int n_in,
                              void* d_out, int out_size, void* d_ws, size_t ws_size,
                              hipStream_t stream)
{
    (void)in_sizes; (void)n_in; (void)out_size; (void)ws_size;
    const float* l0_xyz = (const float*)d_in[0];
    const float* l0_pts = (const float*)d_in[1];
    const float* w11 = (const float*)d_in[2];  const float* b11 = (const float*)d_in[3];
    const float* g11 = (const float*)d_in[4];  const float* be11 = (const float*)d_in[5];
    const float* w12 = (const float*)d_in[6];  const float* b12 = (const float*)d_in[7];
    const float* g12 = (const float*)d_in[8];  const float* be12 = (const float*)d_in[9];
    const float* w21 = (const float*)d_in[10]; const float* b21 = (const float*)d_in[11];
    const float* g21 = (const float*)d_in[12]; const float* be21 = (const float*)d_in[13];
    const float* w22 = (const float*)d_in[14]; const float* b22 = (const float*)d_in[15];
    const float* g22 = (const float*)d_in[16]; const float* be22 = (const float*)d_in[17];
    const float* w31 = (const float*)d_in[18]; const float* b31 = (const float*)d_in[19];
    const float* g31 = (const float*)d_in[20]; const float* be31 = (const float*)d_in[21];
    const float* w32 = (const float*)d_in[22]; const float* b32 = (const float*)d_in[23];
    const float* g32 = (const float*)d_in[24]; const float* be32 = (const float*)d_in[25];

    float* out = (float*)d_out;
    float* o_l1xyz = out;                 // (16,3,256)
    float* o_l1pts = out + 12288;         // (16,128,256)
    float* o_l2xyz = out + 536576;        // (16,3,128)
    float* o_l2pts = out + 542720;        // (16,256,128)
    float* o_l3xyz = out + 1067008;       // (16,3,1)
    float* o_x     = out + 1067056;       // (16,512)

    char* ws = (char*)d_ws;
    size_t off = 0;
    auto alloc = [&](size_t bytes) {
        void* r = ws + off;
        off += ((bytes + 255) & ~(size_t)255);
        return r;
    };
    float* nxyz1 = (float*)alloc(12288 * 4);
    float* nxyz2 = (float*)alloc(6144 * 4);
    int*   gi1   = (int*)alloc(131072 * 4);
    int*   gi2   = (int*)alloc(131072 * 4);
    float* p1    = (float*)alloc(4194304 * 4);
    float* q1    = (float*)alloc(262144 * 4);
    float* mx1   = (float*)alloc(524288 * 4);
    float* mn1   = (float*)alloc(524288 * 4);
    float* p2    = (float*)alloc(524288 * 4);
    float* q2    = (float*)alloc(262144 * 4);
    float* mx2   = (float*)alloc(524288 * 4);
    float* mn2   = (float*)alloc(524288 * 4);
    float* h31   = (float*)alloc(524288 * 4);
    float* mx3   = (float*)alloc(8192 * 4);
    float* mn3   = (float*)alloc(8192 * 4);
    float* stats = (float*)alloc(129024 * 4);
    float* st1a = stats;                 // 16*2*64
    float* st2a = st1a + 2048;           // 64*2*128
    float* st1b = st2a + 16384;          // 16*2*128
    float* st2b = st1b + 4096;           // 64*2*256
    float* st3a = st2b + 32768;          // 16*2*256
    float* st3b = st3a + 8192;           // 64*2*512
    unsigned short* w12t = (unsigned short*)alloc(128 * 64 * 2);
    unsigned short* w22t = (unsigned short*)alloc(256 * 128 * 2);
    unsigned short* w32t = (unsigned short*)alloc(512 * 256 * 2);

    // L1: fps1 + project6 + weight transposes + stats zero
    mega1_kernel<<<8796, 512, 0, stream>>>(l0_xyz, l0_pts, w11, b11, p1,
                                           nxyz1, o_l1xyz,
                                           w12, w12t, w22, w22t, w32, w32t, stats);
    // L2: fps2 (16 waves) + ballquery/stats SA1 (4096 waves) @ 4 waves/block
    ballstat_kernel<32, 64, true><<<1028, 256, 0, stream>>>(
        l0_xyz, 3 * 4096, 4096, 1, 4096, nxyz1, 256, 0.04f, gi1, w11, q1, p1, st1a,
        nxyz1, nxyz2, o_l2xyz);
    // L3: SA1 layer2 MFMA (+BN1 finalize inline)
    mfma_gemm_kernel<32, 64, 128><<<4096, 512, 0, stream>>>(
        p1, q1, gi1, 256, 1, 4096, st1a, 131072.0f, g11, be11, w12t, 128, b12,
        st2a, mx1, mn1);
    // L4: proj2 (64 blocks, feat1 on the fly) + apply1 (64 blocks -> o_l1pts)
    applyproj_kernel<false><<<128, 512, 0, stream>>>(
        nxyz1, mx1, mn1, st2a, g12, be12, 131072.0f, 256, 128, w21, 128, b21, p2,
        nullptr, 64,
        st2a, 128, 131072.0f, g12, be12, mx1, mn1, 256, o_l1pts, 524288);
    // L5: ballquery/stats SA2 @ 4 waves/block
    ballstat_kernel<64, 128, false><<<512, 256, 0, stream>>>(
        nxyz1, 768, 1, 3, 256, nxyz2, 128, 0.0625f, gi2, w21, q2, p2, st1b,
        nullptr, nullptr, nullptr);
    // L6: SA2 layer2 MFMA
    mfma_gemm_kernel<64, 128, 256><<<2048, 512, 0, stream>>>(
        p2, q2, gi2, 128, 1, 256, st1b, 131072.0f, g21, be21, w22t, 256, b22,
        st2b, mx2, mn2);
    // L7: proj3 (64 blocks, feat2 on the fly, + SA3 BN1 stats) + apply2 (64 blocks)
    applyproj_kernel<true><<<128, 512, 0, stream>>>(
        nxyz2, mx2, mn2, st2b, g22, be22, 131072.0f, 128, 256, w31, 256, b31, h31,
        st3a, 64,
        st2b, 256, 131072.0f, g22, be22, mx2, mn2, 128, o_l2pts, 524288);
    // L8: SA3 layer2 MFMA
    mfma_gemm_kernel<128, 256, 128><<<64, 512, 0, stream>>>(
        h31, nullptr, nullptr, 1, 4, 0, st3a, 2048.0f, g31, be31, w32t, 512, b32,
        st3b, mx3, mn3);
    // L9: final apply -> o_x, zero o_l3xyz
    apply3_kernel<<<16, 512, 0, stream>>>(st3b, 512, 2048.0f, g32, be32, mx3, mn3,
                                          1, o_x, 8192, o_l3xyz);
}

// Round 11
// 528.125 us; speedup vs baseline: 1.1930x; 1.0647x over previous
//
#include <hip/hip_runtime.h>
#include <cstddef>

// PointNet++ set-abstraction pipeline (B=16, N=4096, HC=64).
// R11: fps reverted to the R4/R6 empirical optimum (reg coord arrays +
// b32 LDS mirror + parity key-slot merge; compiler remats coords via L1
// global loads which pipeline better than any LDS variant we tried —
// R7/R9/R10 all regressed). New: float4-packed scan sources for the ball
// queries (pxyz4 from project6, nxyz4 from fps1) — 1 coalesced 16B load
// per scanned point instead of 3 b32 loads; arithmetic bit-identical.

#define EPSB 1e-5f
constexpr int SLOTS1 = 16;
constexpr int SLOTS2 = 64;

static __device__ __forceinline__ unsigned long long umax64(unsigned long long a,
                                                            unsigned long long b)
{
    return a > b ? a : b;
}

static __device__ __forceinline__ unsigned pack_bf16x2(float a, float b)
{
    unsigned ua = __float_as_uint(a), ub = __float_as_uint(b);
    ua += 0x7fffu + ((ua >> 16) & 1u);
    ub += 0x7fffu + ((ub >> 16) & 1u);
    return (ua >> 16) | (ub & 0xffff0000u);
}

static __device__ __forceinline__ unsigned short bf16_of(float a)
{
    unsigned u = __float_as_uint(a);
    u += 0x7fffu + ((u >> 16) & 1u);
    return (unsigned short)(u >> 16);
}

// Full-wave u64 max via DPP (row_shr 1/2/4/8 + row_bcast15/31), broadcast to
// all lanes via readlane 63. All 64 lanes must be active.
static __device__ __forceinline__ unsigned long long wave_umax64_dpp(unsigned long long x)
{
#define DPP_STEP(ctrl, rmask)                                                        \
    {                                                                                \
        int lo_ = __builtin_amdgcn_update_dpp(0, (int)(unsigned)x, ctrl, rmask, 0xf, false); \
        int hi_ = __builtin_amdgcn_update_dpp(0, (int)(unsigned)(x >> 32), ctrl, rmask, 0xf, false); \
        unsigned long long c_ = ((unsigned long long)(unsigned)hi_ << 32) | (unsigned)lo_; \
        x = umax64(x, c_);                                                           \
    }
    DPP_STEP(0x111, 0xf)
    DPP_STEP(0x112, 0xf)
    DPP_STEP(0x114, 0xf)
    DPP_STEP(0x118, 0xf)
    DPP_STEP(0x142, 0xa)
    DPP_STEP(0x143, 0xc)
#undef DPP_STEP
    unsigned lo = (unsigned)__builtin_amdgcn_readlane((int)(unsigned)x, 63);
    unsigned hi = (unsigned)__builtin_amdgcn_readlane((int)(unsigned)(x >> 32), 63);
    return ((unsigned long long)hi << 32) | lo;
}

// ---------------- FPS body (R4-exact structure) ----------------
// jax scan semantics: idx[0]=0; dist=min(dist,|x-c|^2); next=argmax (first-index
// ties). Key: hi = dist bits (>=0), lo = ~gidx (max -> smallest index).
template<int N, int NPOINT, int THREADS>
__device__ __forceinline__ void fps_body(int t,
        float* sx, float* sy, float* sz, unsigned long long* kslots,
        const float* __restrict__ xyz, int bStride, int cStride, int nStride,
        int b, float* __restrict__ nxyz, float* __restrict__ lxyz,
        float4* __restrict__ n4out)
{
    constexpr int PT = N / THREADS;
    constexpr int NW = THREADS / 64;
    constexpr int NSTASH = (NPOINT + THREADS - 1) / THREADS;
    const float* xb = xyz + (size_t)b * bStride;

    float px[PT], py[PT], pz[PT], dist[PT];
#pragma unroll
    for (int i = 0; i < PT; ++i) {
        int p = t + i * THREADS;
        px[i] = xb[(size_t)0 * cStride + (size_t)p * nStride];
        py[i] = xb[(size_t)1 * cStride + (size_t)p * nStride];
        pz[i] = xb[(size_t)2 * cStride + (size_t)p * nStride];
        if constexpr (NW > 1) { sx[p] = px[i]; sy[p] = py[i]; sz[p] = pz[i]; }
        dist[i] = 1e10f;
    }

    float stx[NSTASH], sty[NSTASH], stz[NSTASH];
#pragma unroll
    for (int i = 0; i < NSTASH; ++i) { stx[i] = 0.f; sty[i] = 0.f; stz[i] = 0.f; }

    // round 0 = point 0 (uniform scalar loads)
    float cx = xb[0], cy = xb[(size_t)cStride], cz = xb[(size_t)2 * cStride];
    if (t == 0) { stx[0] = cx; sty[0] = cy; stz[0] = cz; }
    if constexpr (NW > 1) __syncthreads();   // mirror ready

    for (int it = 1; it < NPOINT; ++it) {
        float bv = -1.0f; int bidx = 0;
        float bx = 0.f, by = 0.f, bz = 0.f;   // used only in NW==1 path
#pragma unroll
        for (int i = 0; i < PT; ++i) {
            float dx = px[i] - cx, dy = py[i] - cy, dz = pz[i] - cz;
            float d = __builtin_fmaf(dx, dx, __builtin_fmaf(dy, dy, dz * dz));
            float nd = fminf(dist[i], d);
            dist[i] = nd;
            bool g = nd > bv;      // strict >: keeps lowest index within lane
            bv = g ? nd : bv;
            bidx = g ? (t + i * THREADS) : bidx;
            if constexpr (NW == 1) {
                bx = g ? px[i] : bx; by = g ? py[i] : by; bz = g ? pz[i] : bz;
            }
        }
        unsigned long long mykey =
            ((unsigned long long)__float_as_uint(bv) << 32) | (unsigned)(~bidx);
        unsigned long long wkey = wave_umax64_dpp(mykey);
        if constexpr (NW > 1) {
            const int pb = it & 1;
            if ((t & 63) == 0) kslots[pb * NW + (t >> 6)] = wkey;
            __syncthreads();
            unsigned long long m = kslots[pb * NW + 0];
#pragma unroll
            for (int w2 = 1; w2 < NW; ++w2) m = umax64(m, kslots[pb * NW + w2]);
            int widx = (int)(~(unsigned)m);
            cx = sx[widx]; cy = sy[widx]; cz = sz[widx];   // broadcast b32 reads
        } else {
            unsigned long long ball = __ballot(mykey == wkey);
            int wl = __ffsll(ball) - 1;   // uniform winner lane
            cx = __int_as_float(__builtin_amdgcn_readlane(__float_as_int(bx), wl));
            cy = __int_as_float(__builtin_amdgcn_readlane(__float_as_int(by), wl));
            cz = __int_as_float(__builtin_amdgcn_readlane(__float_as_int(bz), wl));
        }
        if constexpr (NSTASH == 1) {
            if (t == it) { stx[0] = cx; sty[0] = cy; stz[0] = cz; }
        } else {
            if ((it & (THREADS - 1)) == t) {
                if (it >= THREADS) { stx[1] = cx; sty[1] = cy; stz[1] = cz; }
                else               { stx[0] = cx; sty[0] = cy; stz[0] = cz; }
            }
        }
    }
#pragma unroll
    for (int s2 = 0; s2 < NSTASH; ++s2) {
        int s = t + s2 * THREADS;
        if (s < NPOINT) {
            nxyz[(size_t)(b * NPOINT + s) * 3 + 0] = stx[s2];
            nxyz[(size_t)(b * NPOINT + s) * 3 + 1] = sty[s2];
            nxyz[(size_t)(b * NPOINT + s) * 3 + 2] = stz[s2];
            lxyz[(size_t)b * 3 * NPOINT + 0 * NPOINT + s] = stx[s2];
            lxyz[(size_t)b * 3 * NPOINT + 1 * NPOINT + s] = sty[s2];
            lxyz[(size_t)b * 3 * NPOINT + 2 * NPOINT + s] = stz[s2];
            if (n4out) n4out[(size_t)b * NPOINT + s] = make_float4(stx[s2], sty[s2], stz[s2], 0.f);
        }
    }
}

// ---------------- Mega-kernel 1: fps1 + project6(+pxyz4) + w2t x3 + stats-zero --------
__global__ __launch_bounds__(512)
void mega1_kernel(const float* __restrict__ l0_xyz, const float* __restrict__ l0_pts,
                  const float* __restrict__ w11, const float* __restrict__ b11,
                  float* __restrict__ p1, float4* __restrict__ pxyz4,
                  float* __restrict__ nxyz1, float4* __restrict__ nxyz4,
                  float* __restrict__ o_l1xyz,
                  const float* __restrict__ w12, unsigned short* __restrict__ w12t,
                  const float* __restrict__ w22, unsigned short* __restrict__ w22t,
                  const float* __restrict__ w32, unsigned short* __restrict__ w32t,
                  float* __restrict__ stats)
{
    __shared__ float smx[4096], smy[4096], smz[4096];
    __shared__ __attribute__((aligned(16))) unsigned long long kxs[16];
    int blk = blockIdx.x;
    const int tid = threadIdx.x;
    if (blk < 16) {
        fps_body<4096, 256, 512>(tid, smx, smy, smz, kxs,
                                 l0_xyz, 3 * 4096, 4096, 1, blk, nxyz1, o_l1xyz, nxyz4);
        return;
    }
    blk -= 16;
    if (blk < 8192) {  // project6: p1[b,n,64] = [xyz,pts]·W1 + b1 ; also pack pxyz4
        int idx = blk * 512 + tid;
        int d = idx & 63;
        int n = (idx >> 6) & 4095;
        int b = idx >> 18;
        const float* xb = l0_xyz + (size_t)b * 3 * 4096 + n;
        const float* pb = l0_pts + (size_t)b * 3 * 4096 + n;
        float a0 = xb[0], a1 = xb[4096], a2 = xb[2 * 4096];
        float a3 = pb[0], a4 = pb[4096], a5 = pb[2 * 4096];
        float acc = b11[d];
        acc += a0 * w11[d] + a1 * w11[64 + d] + a2 * w11[128 + d];
        acc += a3 * w11[192 + d] + a4 * w11[256 + d] + a5 * w11[320 + d];
        p1[idx] = acc;
        if (d == 0) pxyz4[(size_t)b * 4096 + n] = make_float4(a0, a1, a2, 0.f);
        return;
    }
    blk -= 8192;
    if (blk < 16) {
        int i = blk * 512 + tid;
        if (i < 64 * 128) { int k = i / 128, n = i % 128; w12t[(size_t)n * 64 + k] = bf16_of(w12[i]); }
        return;
    }
    blk -= 16;
    if (blk < 64) {
        int i = blk * 512 + tid;
        if (i < 128 * 256) { int k = i / 256, n = i % 256; w22t[(size_t)n * 128 + k] = bf16_of(w22[i]); }
        return;
    }
    blk -= 64;
    if (blk < 256) {
        int i = blk * 512 + tid;
        if (i < 256 * 512) { int k = i / 512, n = i % 512; w32t[(size_t)n * 256 + k] = bf16_of(w32[i]); }
        return;
    }
    blk -= 256;
    {
        int i = blk * 512 + tid;
        if (i < 129024) stats[i] = 0.f;
    }
}

// ---------------- Ball query + q projection + fused BN1 stats (+opt fps2) -------------
// 256 threads = 4 waves; one ball per wave. Scan source: float4-packed points.
template<int NS, int D, bool WITHFPS>
__global__ __launch_bounds__(256)
void ballstat_kernel(const float4* __restrict__ pts4base, int N,
                     const float* __restrict__ nxyz, int S, float r2,
                     int* __restrict__ gi,
                     const float* __restrict__ W, float* __restrict__ q,
                     const float* __restrict__ p, float* __restrict__ slots,
                     const float* __restrict__ fxyz, float* __restrict__ fnxyz,
                     float* __restrict__ flxyz)
{
    __shared__ int sgo[4][NS];
    const int wid = threadIdx.x >> 6, l = threadIdx.x & 63;
    int g = blockIdx.x * 4 + wid;
    if constexpr (WITHFPS) {
        if (g < 16) {
            fps_body<256, 128, 64>(l, nullptr, nullptr, nullptr, nullptr,
                                   fxyz, 768, 1, 3, g, fnxyz, flxyz, nullptr);
            return;
        }
        g -= 16;
    }
    constexpr int DL = D / 64;
    const int bs = g;
    const int b = bs / S;
    float cx = nxyz[(size_t)bs * 3 + 0], cy = nxyz[(size_t)bs * 3 + 1], cz = nxyz[(size_t)bs * 3 + 2];
    float s2 = cx * cx + cy * cy + cz * cz;
    const float4* xb4 = pts4base + (size_t)b * N;
    int cnt = 0;
    int first = N - 1;
    int* go = gi + (size_t)bs * NS;
    for (int base = 0; base < N; base += 64) {
        int n = base + l;
        float4 c4 = xb4[n];   // one coalesced 16B load
        float x = c4.x, y = c4.y, z = c4.z;
        float x2 = x * x + y * y + z * z;        // identical expression to prior rounds
        float dot = cx * x + cy * y + cz * z;
        float sqr = (s2 + x2) - 2.0f * dot;      // reference expansion form
        bool pass = (sqr <= r2);
        unsigned long long m = __ballot(pass);
        if (cnt == 0 && m) first = base + (__ffsll((unsigned long long)m) - 1);
        int pos = cnt + __popcll(m & ((1ull << l) - 1ull));
        if (pass && pos < NS) { go[pos] = n; sgo[wid][pos] = n; }
        cnt += __popcll(m);
        if (cnt >= NS) break;
    }
    if (cnt < NS && l >= cnt && l < NS) { go[l] = first; sgo[wid][l] = first; }

    float qv[DL];
#pragma unroll
    for (int j = 0; j < DL; ++j) {
        int d = j * 64 + l;
        qv[j] = cx * W[d] + cy * W[D + d] + cz * W[2 * D + d];
        q[(size_t)bs * D + d] = qv[j];
    }
    float s[DL], ss[DL];
#pragma unroll
    for (int j = 0; j < DL; ++j) { s[j] = 0.f; ss[j] = 0.f; }
#pragma unroll 4
    for (int k = 0; k < NS; ++k) {
        int idx = sgo[wid][k];
        const float* pr = p + (size_t)(b * N + idx) * D;
#pragma unroll
        for (int j = 0; j < DL; ++j) {
            float v = pr[j * 64 + l] - qv[j];
            s[j] += v; ss[j] += v * v;
        }
    }
    int slot = bs & (SLOTS1 - 1);
#pragma unroll
    for (int j = 0; j < DL; ++j) {
        int d = j * 64 + l;
        atomicAdd(&slots[(size_t)(slot * 2 + 0) * D + d], s[j]);
        atomicAdd(&slots[(size_t)(slot * 2 + 1) * D + d], ss[j]);
    }
}

// ---------------- MFMA layer-2 with inline BN1 finalize ----------------
template<int KS, int CIN, int COUTB>
__global__ __launch_bounds__(512, 2)
void mfma_gemm_kernel(const float* __restrict__ p, const float* __restrict__ q,
                      const int* __restrict__ gi, int S, int NCH, int N,
                      const float* __restrict__ st1, float m1cnt,
                      const float* __restrict__ g1, const float* __restrict__ be1,
                      const unsigned short* __restrict__ w2t, int coutFull,
                      const float* __restrict__ b2,
                      float* __restrict__ st2,
                      float* __restrict__ mx, float* __restrict__ mn)
{
    constexpr int MT = KS / 16;
    constexpr int NSL = 8 / MT;
    constexpr int SLW = COUTB / NSL;
    constexpr int TPW = SLW / 16;
    constexpr int KST = CIN / 32;
    constexpr int LDA = CIN + 8;
    typedef __attribute__((ext_vector_type(8))) short bf16x8;
    typedef __attribute__((ext_vector_type(4))) float f32x4;

    __shared__ __attribute__((aligned(16))) unsigned short hl[KS][LDA];
    __shared__ float red[4][8][SLW];
    __shared__ __attribute__((aligned(16))) float ss_scale[CIN];
    __shared__ __attribute__((aligned(16))) float ss_shift[CIN];

    const int chunk = blockIdx.x % NCH;
    const int bs = blockIdx.x / NCH;
    const int b = bs / S;
    const int tid = threadIdx.x;
    const int c2_0 = chunk * COUTB;
    const int w = tid >> 6, lane = tid & 63;
    const int mt = w % MT, ns = w / MT;
    const int lrow = lane & 15, quad = lane >> 4;

    for (int c = tid; c < CIN; c += 512) {
        float s0 = 0.f, s1 = 0.f;
        for (int sl = 0; sl < SLOTS1; ++sl) {
            s0 += st1[(size_t)(sl * 2 + 0) * CIN + c];
            s1 += st1[(size_t)(sl * 2 + 1) * CIN + c];
        }
        float mean = s0 / m1cnt;
        float var = s1 / m1cnt - mean * mean;
        float inv = 1.0f / sqrtf(var + EPSB);
        float scl = g1[c] * inv;
        ss_scale[c] = scl;
        ss_shift[c] = be1[c] - scl * mean;
    }
    __syncthreads();

    constexpr int ITER = KS * CIN / (512 * 4);
    const int gbase = bs * KS;
#pragma unroll
    for (int it = 0; it < ITER; ++it) {
        int e = (it * 512 + tid) * 4;
        int k = e / CIN, c = e % CIN;
        int row = gi ? (b * N + gi[gbase + k]) : (b * KS + k);
        float4 v = *(const float4*)&p[(size_t)row * CIN + c];
        if (q) {
            float4 qq = *(const float4*)&q[(size_t)bs * CIN + c];
            v.x -= qq.x; v.y -= qq.y; v.z -= qq.z; v.w -= qq.w;
        }
        float4 sc = *(const float4*)&ss_scale[c];
        float4 sh = *(const float4*)&ss_shift[c];
        v.x = fmaxf(__builtin_fmaf(sc.x, v.x, sh.x), 0.f);
        v.y = fmaxf(__builtin_fmaf(sc.y, v.y, sh.y), 0.f);
        v.z = fmaxf(__builtin_fmaf(sc.z, v.z, sh.z), 0.f);
        v.w = fmaxf(__builtin_fmaf(sc.w, v.w, sh.w), 0.f);
        uint2 pk;
        pk.x = pack_bf16x2(v.x, v.y);
        pk.y = pack_bf16x2(v.z, v.w);
        *(uint2*)&hl[k][c] = pk;
    }
    __syncthreads();

    f32x4 acc[TPW];
#pragma unroll
    for (int t = 0; t < TPW; ++t) acc[t] = (f32x4){0.f, 0.f, 0.f, 0.f};

    const int nbase = c2_0 + ns * SLW + lrow;
#pragma unroll
    for (int ks = 0; ks < KST; ++ks) {
        bf16x8 a = *(const bf16x8*)&hl[mt * 16 + lrow][ks * 32 + quad * 8];
#pragma unroll
        for (int t = 0; t < TPW; ++t) {
            bf16x8 bfr = *(const bf16x8*)&w2t[(size_t)(nbase + t * 16) * CIN + ks * 32 + quad * 8];
            acc[t] = __builtin_amdgcn_mfma_f32_16x16x32_bf16(a, bfr, acc[t], 0, 0, 0);
        }
    }

#pragma unroll
    for (int t = 0; t < TPW; ++t) {
        float bias = b2[nbase + t * 16];
        float s = 0.f, sq = 0.f, amx = -3.4e38f, amn = 3.4e38f;
#pragma unroll
        for (int r = 0; r < 4; ++r) {
            float v = acc[t][r] + bias;
            s += v; sq += v * v;
            amx = fmaxf(amx, v); amn = fminf(amn, v);
        }
#pragma unroll
        for (int off = 16; off < 64; off <<= 1) {
            s += __shfl_xor(s, off);
            sq += __shfl_xor(sq, off);
            amx = fmaxf(amx, __shfl_xor(amx, off));
            amn = fminf(amn, __shfl_xor(amn, off));
        }
        if (quad == 0) {
            int lc = t * 16 + lrow;
            red[0][w][lc] = s; red[1][w][lc] = sq;
            red[2][w][lc] = amx; red[3][w][lc] = amn;
        }
    }
    __syncthreads();
    for (int c = tid; c < COUTB; c += 512) {
        int ns2 = c / SLW, lc = c % SLW;
        float s = 0.f, sq = 0.f, amx = -3.4e38f, amn = 3.4e38f;
#pragma unroll
        for (int m2 = 0; m2 < MT; ++m2) {
            int w2 = ns2 * MT + m2;
            s += red[0][w2][lc]; sq += red[1][w2][lc];
            amx = fmaxf(amx, red[2][w2][lc]);
            amn = fminf(amn, red[3][w2][lc]);
        }
        int slot = blockIdx.x & (SLOTS2 - 1);
        atomicAdd(&st2[(size_t)(slot * 2 + 0) * coutFull + c2_0 + c], s);
        atomicAdd(&st2[(size_t)(slot * 2 + 1) * coutFull + c2_0 + c], sq);
        mx[(size_t)bs * coutFull + c2_0 + c] = amx;
        mn[(size_t)bs * coutFull + c2_0 + c] = amn;
    }
}

// ---------------- apply body ----------------
__device__ __forceinline__ void apply_body(char* smraw, int blk, int nblk,
        const float* __restrict__ st2, int C, float cnt,
        const float* __restrict__ g2, const float* __restrict__ be2,
        const float* __restrict__ mx, const float* __restrict__ mn,
        int S, float* __restrict__ outT, int total, float* __restrict__ zero48)
{
    float* sc = (float*)smraw;
    float* sh = sc + 512;
    for (int c = threadIdx.x; c < C; c += 512) {
        float s0 = 0.f, s1 = 0.f;
        for (int sl = 0; sl < SLOTS2; ++sl) {
            s0 += st2[(size_t)(sl * 2 + 0) * C + c];
            s1 += st2[(size_t)(sl * 2 + 1) * C + c];
        }
        float mean = s0 / cnt;
        float var = s1 / cnt - mean * mean;
        float inv = 1.0f / sqrtf(var + EPSB);
        float scl = g2[c] * inv;
        sc[c] = scl; sh[c] = be2[c] - scl * mean;
    }
    __syncthreads();
    if (zero48 && blk == 0 && threadIdx.x < 48) zero48[threadIdx.x] = 0.f;
    for (int e = blk * 512 + threadIdx.x; e < total; e += nblk * 512) {
        int s = e % S;
        int rem = e / S;
        int c = rem % C;
        int b = rem / C;
        float scl = sc[c];
        size_t mi = (size_t)(b * S + s) * C + c;
        float v = (scl >= 0.f) ? mx[mi] : mn[mi];   // maxpool commutes through monotone BN
        outT[e] = fmaxf(scl * v + sh[c], 0.f);
    }
}

// ---------------- proj body: [xyz, BN2(mx/mn) feat] · W + bias (+opt SA3 stats) -------
template<int COUTB, bool DOSTATS>
__device__ __forceinline__ void proj_body(char* smraw, int blk,
        const float* __restrict__ xyzsrc,
        const float* __restrict__ mxF, const float* __restrict__ mnF,
        const float* __restrict__ stF, const float* __restrict__ gF,
        const float* __restrict__ beF, float cntF,
        int N, int CF, const float* __restrict__ W, int coutFull,
        const float* __restrict__ bias, float* __restrict__ outp,
        float* __restrict__ st3)
{
    constexpr int BK = 32, BKP = 36, TK = 4, TC = 4, THREADS = 512, ROWS = 64;
    constexpr int C2G = COUTB / TC;
    float (*al)[BKP] = (float (*)[BKP])smraw;
    float (*wl)[BKP] = (float (*)[BKP])(smraw + ROWS * BKP * 4);
    float* scF = (float*)(smraw + (ROWS + COUTB) * BKP * 4);
    float* shF = scF + CF;
    float* red2 = shF + CF;
    const int NCH = coutFull / COUTB;
    const int chunk = blk % NCH;
    const int rb = blk / NCH;
    const int m0 = rb * ROWS;
    const int c2_0 = chunk * COUTB;
    const int K = CF + 3;
    const int tid = threadIdx.x;
    const int c2g = tid % C2G, kt = tid / C2G;

    for (int c = tid; c < CF; c += THREADS) {
        float s0 = 0.f, s1 = 0.f;
        for (int sl = 0; sl < SLOTS2; ++sl) {
            s0 += stF[(size_t)(sl * 2 + 0) * CF + c];
            s1 += stF[(size_t)(sl * 2 + 1) * CF + c];
        }
        float mean = s0 / cntF;
        float var = s1 / cntF - mean * mean;
        float inv = 1.0f / sqrtf(var + EPSB);
        float scl = gF[c] * inv;
        scF[c] = scl; shF[c] = beF[c] - scl * mean;
    }

    float acc[TK][TC];
#pragma unroll
    for (int i = 0; i < TK; ++i)
#pragma unroll
        for (int j = 0; j < TC; ++j) acc[i][j] = 0.f;
    const int npan = (K + BK - 1) / BK;
    for (int pan = 0; pan < npan; ++pan) {
        __syncthreads();
        const int cbase = pan * BK;
        for (int e = tid; e < ROWS * BK; e += THREADS) {
            int rl = e / BK, cl = e % BK;
            int c = cbase + cl;
            int m = m0 + rl;
            float v = 0.f;
            if (c < 3) v = xyzsrc[(size_t)m * 3 + c];
            else if (c < K) {
                int cf = c - 3;
                float scl = scF[cf];
                size_t mi = (size_t)m * CF + cf;
                float pick = (scl >= 0.f) ? mxF[mi] : mnF[mi];
                v = fmaxf(scl * pick + shF[cf], 0.f);
            }
            al[rl][cl] = v;
        }
        for (int e = tid; e < COUTB * BK; e += THREADS) {
            int c2 = e % COUTB, cl = e / COUTB;
            int c = cbase + cl;
            wl[c2][cl] = (c < K) ? W[(size_t)c * coutFull + c2_0 + c2] : 0.f;
        }
        __syncthreads();
#pragma unroll
        for (int cl = 0; cl < BK; cl += 4) {
            float4 av[TK], wv[TC];
#pragma unroll
            for (int i = 0; i < TK; ++i) av[i] = *(const float4*)&al[kt * TK + i][cl];
#pragma unroll
            for (int j = 0; j < TC; ++j) wv[j] = *(const float4*)&wl[c2g + j * C2G][cl];
#pragma unroll
            for (int i = 0; i < TK; ++i)
#pragma unroll
                for (int j = 0; j < TC; ++j)
                    acc[i][j] += av[i].x * wv[j].x + av[i].y * wv[j].y
                               + av[i].z * wv[j].z + av[i].w * wv[j].w;
        }
    }
    float ps[TC], pq[TC];
#pragma unroll
    for (int j = 0; j < TC; ++j) {
        float bb_ = bias[c2_0 + c2g + j * C2G];
        float s = 0.f, sq = 0.f;
#pragma unroll
        for (int i = 0; i < TK; ++i) {
            int m = m0 + kt * TK + i;
            float v = acc[i][j] + bb_;
            outp[(size_t)m * coutFull + c2_0 + c2g + j * C2G] = v;
            s += v; sq += v * v;
        }
        ps[j] = s; pq[j] = sq;
    }
    if constexpr (DOSTATS) {
        const int w = tid >> 6, lane = tid & 63;
#pragma unroll
        for (int j = 0; j < TC; ++j) {
            ps[j] += __shfl_xor(ps[j], 32);
            pq[j] += __shfl_xor(pq[j], 32);
            if (lane < 32) {
                int c2 = c2g + j * C2G;
                red2[(w * COUTB + c2) * 2 + 0] = ps[j];
                red2[(w * COUTB + c2) * 2 + 1] = pq[j];
            }
        }
        __syncthreads();
        for (int c = tid; c < COUTB; c += THREADS) {
            float s = 0.f, sq = 0.f;
#pragma unroll
            for (int w2 = 0; w2 < 8; ++w2) {
                s += red2[(w2 * COUTB + c) * 2 + 0];
                sq += red2[(w2 * COUTB + c) * 2 + 1];
            }
            int slot = blk & (SLOTS1 - 1);
            atomicAdd(&st3[(size_t)(slot * 2 + 0) * coutFull + c2_0 + c], s);
            atomicAdd(&st3[(size_t)(slot * 2 + 1) * coutFull + c2_0 + c], sq);
        }
    }
}

// ---------------- Fused apply + proj launches ----------------
template<bool DOSTATS>
__global__ __launch_bounds__(512, 2)
void applyproj_kernel(
        const float* __restrict__ xyzsrc,
        const float* __restrict__ mxF, const float* __restrict__ mnF,
        const float* __restrict__ stF, const float* __restrict__ gF,
        const float* __restrict__ beF, float cntF,
        int Nrows, int CF, const float* __restrict__ W, int coutFull,
        const float* __restrict__ bias, float* __restrict__ outp,
        float* __restrict__ st3, int projBlocks,
        const float* __restrict__ st2, int C, float m2cnt,
        const float* __restrict__ g2, const float* __restrict__ be2,
        const float* __restrict__ mxA, const float* __restrict__ mnA,
        int S, float* __restrict__ outT, int total)
{
    __shared__ __attribute__((aligned(16))) char arena[38144];
    if ((int)blockIdx.x < projBlocks)
        proj_body<128, DOSTATS>(arena, blockIdx.x, xyzsrc, mxF, mnF, stF, gF, beF, cntF,
                                Nrows, CF, W, coutFull, bias, outp, st3);
    else
        apply_body(arena, blockIdx.x - projBlocks, gridDim.x - projBlocks,
                   st2, C, m2cnt, g2, be2, mxA, mnA, S, outT, total, nullptr);
}

__global__ __launch_bounds__(512, 2)
void apply3_kernel(const float* __restrict__ st2, int C, float cnt,
                   const float* __restrict__ g2, const float* __restrict__ be2,
                   const float* __restrict__ mx, const float* __restrict__ mn,
                   int S, float* __restrict__ outT, int total, float* __restrict__ zero48)
{
    __shared__ __attribute__((aligned(16))) char arena[4160];
    apply_body(arena, blockIdx.x, gridDim.x, st2, C, cnt, g2, be2, mx, mn, S, outT, total, zero48);
}

extern "C" void kernel_launch(void* const* d_in, const int* in_sizes, int n_in,
                              void* d_out, int out_size, void* d_ws, size_t ws_size,
                              hipStream_t stream)
{
    (void)in_sizes; (void)n_in; (void)out_size; (void)ws_size;
    const float* l0_xyz = (const float*)d_in[0];
    const float* l0_pts = (const float*)d_in[1];
    const float* w11 = (const float*)d_in[2];  const float* b11 = (const float*)d_in[3];
    const float* g11 = (const float*)d_in[4];  const float* be11 = (const float*)d_in[5];
    const float* w12 = (const float*)d_in[6];  const float* b12 = (const float*)d_in[7];
    const float* g12 = (const float*)d_in[8];  const float* be12 = (const float*)d_in[9];
    const float* w21 = (const float*)d_in[10]; const float* b21 = (const float*)d_in[11];
    const float* g21 = (const float*)d_in[12]; const float* be21 = (const float*)d_in[13];
    const float* w22 = (const float*)d_in[14]; const float* b22 = (const float*)d_in[15];
    const float* g22 = (const float*)d_in[16]; const float* be22 = (const float*)d_in[17];
    const float* w31 = (const float*)d_in[18]; const float* b31 = (const float*)d_in[19];
    const float* g31 = (const float*)d_in[20]; const float* be31 = (const float*)d_in[21];
    const float* w32 = (const float*)d_in[22]; const float* b32 = (const float*)d_in[23];
    const float* g32 = (const float*)d_in[24]; const float* be32 = (const float*)d_in[25];

    float* out = (float*)d_out;
    float* o_l1xyz = out;                 // (16,3,256)
    float* o_l1pts = out + 12288;         // (16,128,256)
    float* o_l2xyz = out + 536576;        // (16,3,128)
    float* o_l2pts = out + 542720;        // (16,256,128)
    float* o_l3xyz = out + 1067008;       // (16,3,1)
    float* o_x     = out + 1067056;       // (16,512)

    char* ws = (char*)d_ws;
    size_t off = 0;
    auto alloc = [&](size_t bytes) {
        void* r = ws + off;
        off += ((bytes + 255) & ~(size_t)255);
        return r;
    };
    float* nxyz1 = (float*)alloc(12288 * 4);
    float* nxyz2 = (float*)alloc(6144 * 4);
    float4* nxyz4 = (float4*)alloc(4096 * 16);
    float4* pxyz4 = (float4*)alloc(65536 * 16);
    int*   gi1   = (int*)alloc(131072 * 4);
    int*   gi2   = (int*)alloc(131072 * 4);
    float* p1    = (float*)alloc(4194304 * 4);
    float* q1    = (float*)alloc(262144 * 4);
    float* mx1   = (float*)alloc(524288 * 4);
    float* mn1   = (float*)alloc(524288 * 4);
    float* p2    = (float*)alloc(524288 * 4);
    float* q2    = (float*)alloc(262144 * 4);
    float* mx2   = (float*)alloc(524288 * 4);
    float* mn2   = (float*)alloc(524288 * 4);
    float* h31   = (float*)alloc(524288 * 4);
    float* mx3   = (float*)alloc(8192 * 4);
    float* mn3   = (float*)alloc(8192 * 4);
    float* stats = (float*)alloc(129024 * 4);
    float* st1a = stats;                 // 16*2*64
    float* st2a = st1a + 2048;           // 64*2*128
    float* st1b = st2a + 16384;          // 16*2*128
    float* st2b = st1b + 4096;           // 64*2*256
    float* st3a = st2b + 32768;          // 16*2*256
    float* st3b = st3a + 8192;           // 64*2*512
    unsigned short* w12t = (unsigned short*)alloc(128 * 64 * 2);
    unsigned short* w22t = (unsigned short*)alloc(256 * 128 * 2);
    unsigned short* w32t = (unsigned short*)alloc(512 * 256 * 2);

    // L1: fps1 + project6(+pxyz4) + weight transposes + stats zero
    mega1_kernel<<<8796, 512, 0, stream>>>(l0_xyz, l0_pts, w11, b11, p1, pxyz4,
                                           nxyz1, nxyz4, o_l1xyz,
                                           w12, w12t, w22, w22t, w32, w32t, stats);
    // L2: fps2 (16 waves) + ballquery/stats SA1 (4096 waves) @ 4 waves/block
    ballstat_kernel<32, 64, true><<<1028, 256, 0, stream>>>(
        pxyz4, 4096, nxyz1, 256, 0.04f, gi1, w11, q1, p1, st1a,
        nxyz1, nxyz2, o_l2xyz);
    // L3: SA1 layer2 MFMA (+BN1 finalize inline)
    mfma_gemm_kernel<32, 64, 128><<<4096, 512, 0, stream>>>(
        p1, q1, gi1, 256, 1, 4096, st1a, 131072.0f, g11, be11, w12t, 128, b12,
        st2a, mx1, mn1);
    // L4: proj2 (64 blocks, feat1 on the fly) + apply1 (64 blocks -> o_l1pts)
    applyproj_kernel<false><<<128, 512, 0, stream>>>(
        nxyz1, mx1, mn1, st2a, g12, be12, 131072.0f, 256, 128, w21, 128, b21, p2,
        nullptr, 64,
        st2a, 128, 131072.0f, g12, be12, mx1, mn1, 256, o_l1pts, 524288);
    // L5: ballquery/stats SA2 @ 4 waves/block (scan from packed nxyz4)
    ballstat_kernel<64, 128, false><<<512, 256, 0, stream>>>(
        nxyz4, 256, nxyz2, 128, 0.0625f, gi2, w21, q2, p2, st1b,
        nullptr, nullptr, nullptr);
    // L6: SA2 layer2 MFMA
    mfma_gemm_kernel<64, 128, 256><<<2048, 512, 0, stream>>>(
        p2, q2, gi2, 128, 1, 256, st1b, 131072.0f, g21, be21, w22t, 256, b22,
        st2b, mx2, mn2);
    // L7: proj3 (64 blocks, feat2 on the fly, + SA3 BN1 stats) + apply2 (64 blocks)
    applyproj_kernel<true><<<128, 512, 0, stream>>>(
        nxyz2, mx2, mn2, st2b, g22, be22, 131072.0f, 128, 256, w31, 256, b31, h31,
        st3a, 64,
        st2b, 256, 131072.0f, g22, be22, mx2, mn2, 128, o_l2pts, 524288);
    // L8: SA3 layer2 MFMA
    mfma_gemm_kernel<128, 256, 128><<<64, 512, 0, stream>>>(
        h31, nullptr, nullptr, 1, 4, 0, st3a, 2048.0f, g31, be31, w32t, 512, b32,
        st3b, mx3, mn3);
    // L9: final apply -> o_x, zero o_l3xyz
    apply3_kernel<<<16, 512, 0, stream>>>(st3b, 512, 2048.0f, g32, be32, mx3, mn3,
                                          1, o_x, 8192, o_l3xyz);
}